// Round 5
// baseline (72676.385 us; speedup 1.0000x reference)
//
#include <hip/hip_runtime.h>
#include <stdint.h>

// ============================================================
// AdaptiveLNN on MI355X, round 4: Wrec register+LDS caching.
// Scan is per-CU weight-stream bound (235 GB/s/CU ≈ 77% of L1 return).
// Wrec (62% of bytes) is re-streamed 6x per layer per step; cache
// 21/32 of each thread's Wrec slice (12 uint4 in VGPRs + 9 in LDS),
// filled at unfold 0, reused unfolds 1-5. Stream: 9.9 -> 6.45 MB/step.
// ============================================================

__device__ __forceinline__ float b2f(unsigned short s){
  union { unsigned i; float f; } c; c.i = ((unsigned)s) << 16; return c.f;
}
__device__ __forceinline__ unsigned short f2b(float f){
  union { unsigned i; float f; } c; c.f = f;
  unsigned r = c.i + 0x7fffu + ((c.i >> 16) & 1u);
  return (unsigned short)(r >> 16);
}
__device__ __forceinline__ unsigned pack2(float a, float b){
  return (unsigned)f2b(a) | ((unsigned)f2b(b) << 16);
}
__device__ __forceinline__ float fsig(float x){ return 1.f/(1.f+__expf(-x)); }
__device__ __forceinline__ float ftanh(float x){ return 1.f - 2.f/(__expf(2.f*x)+1.f); }

#if __has_builtin(__builtin_amdgcn_fdot2_f32_bf16)
typedef __bf16 bf16x2_t __attribute__((ext_vector_type(2)));
__device__ __forceinline__ float dot2(unsigned w, unsigned a, float acc){
  union U { unsigned u; bf16x2_t v; };
  U cw; cw.u = w; U ca; ca.u = a;
  return __builtin_amdgcn_fdot2_f32_bf16(cw.v, ca.v, acc, false);
}
#else
__device__ __forceinline__ float dot2(unsigned w, unsigned a, float acc){
  asm("v_dot2_f32_bf16 %0, %1, %2, %0" : "+v"(acc) : "v"(w), "v"(a));
  return acc;
}
#endif

// ---------- streaming full-dot matvec (lane-pair k-split) ----------
// Thread tid: output o = tid>>1, k-half kh = tid&1.
// Weight layout: w[(size_t)i*(2*NOUT) + tid] = 8 bf16 at row o,
// k = (2i+kh)*8 .. +8. act2: packed bf16 pairs.
template<int K, int NOUT>
__device__ __forceinline__ float matvecF(const uint4* __restrict__ w,
                                         const unsigned* __restrict__ act2,
                                         int tid){
  constexpr int NI = K / 16;
  float acc0 = 0.f, acc1 = 0.f;
  const uint4* a4 = (const uint4*)act2;
  const int kh = tid & 1;
  if (tid < 2*NOUT){
    #pragma unroll 8
    for (int i = 0; i < NI; ++i){
      const uint4 wv = w[(size_t)i*(2*NOUT) + tid];
      const uint4 a  = a4[2*i + kh];
      acc0 = dot2(wv.x, a.x, acc0);
      acc0 = dot2(wv.y, a.y, acc0);
      acc1 = dot2(wv.z, a.z, acc1);
      acc1 = dot2(wv.w, a.w, acc1);
    }
  }
  float acc = acc0 + acc1;
  acc += __shfl_xor(acc, 1);
  return acc;
}

// ---------- cached Wrec matvec (K=512, NOUT=512, 1024 threads) ----------
// 32 uint4 per thread: [0,12) registers, [12,21) LDS cache, [21,32) stream.
#define WR_NREG 12
#define WR_NLDS 9
template<bool FILL>
__device__ __forceinline__ float matvecR(const uint4* __restrict__ w,
                                         const unsigned* __restrict__ act2,
                                         uint4 (&wr)[WR_NREG],
                                         uint4* __restrict__ wlds,
                                         int tid){
  float acc0 = 0.f, acc1 = 0.f;
  const uint4* a4 = (const uint4*)act2;
  const int kh = tid & 1;
  #pragma unroll
  for (int i = 0; i < WR_NREG; ++i){
    if (FILL) wr[i] = w[(size_t)i*1024 + tid];
    const uint4 a = a4[2*i + kh];
    acc0 = dot2(wr[i].x, a.x, acc0);
    acc0 = dot2(wr[i].y, a.y, acc0);
    acc1 = dot2(wr[i].z, a.z, acc1);
    acc1 = dot2(wr[i].w, a.w, acc1);
  }
  #pragma unroll
  for (int i = WR_NREG; i < WR_NREG + WR_NLDS; ++i){
    uint4 wv;
    if (FILL){ wv = w[(size_t)i*1024 + tid]; wlds[(i - WR_NREG)*1024 + tid] = wv; }
    else     { wv = wlds[(i - WR_NREG)*1024 + tid]; }
    const uint4 a = a4[2*i + kh];
    acc0 = dot2(wv.x, a.x, acc0);
    acc0 = dot2(wv.y, a.y, acc0);
    acc1 = dot2(wv.z, a.z, acc1);
    acc1 = dot2(wv.w, a.w, acc1);
  }
  #pragma unroll
  for (int i = WR_NREG + WR_NLDS; i < 32; ++i){
    const uint4 wv = w[(size_t)i*1024 + tid];
    const uint4 a  = a4[2*i + kh];
    acc0 = dot2(wv.x, a.x, acc0);
    acc0 = dot2(wv.y, a.y, acc0);
    acc1 = dot2(wv.z, a.z, acc1);
    acc1 = dot2(wv.w, a.w, acc1);
  }
  float acc = acc0 + acc1;
  acc += __shfl_xor(acc, 1);
  return acc;
}

// ---------- one LTC layer, one timestep (scan only; cached Wrec) ----------
template<int FIN>
__device__ __forceinline__ float layer_stepF(
    float& v, float& g,
    const uint4* Wi, const uint4* Wr, const uint4* Ta, const uint4* Tb,
    float wb, float tab, float tbb, float gl, float gs, float lw, float lb,
    unsigned* comb2, unsigned* thA, unsigned* thB, float* sred,
    uint4* wlds, int tid)
{
  float tauh = matvecF<FIN+512, 512>(Ta, comb2, tid);
  float iin  = matvecF<FIN,     512>(Wi, comb2, tid) + wb;
  tauh = ftanh(tauh + tab);
  float hv = ftanh(v);
  {
    const float tp = __shfl_down(tauh, 2);
    const float hp = __shfl_down(hv, 2);
    if (!(tid & 3)){ thA[tid >> 2] = pack2(tauh, tp); thB[tid >> 2] = pack2(hv, hp); }
  }
  __syncthreads();                        // thA (tau_h), thB (tanh v) ready
  float tau = matvecF<512, 512>(Tb, thA, tid);
  tau = 0.1f + 9.9f * fsig(tau + tbb);
  const float ga = 0.2f / tau;
  const float va = 0.1f / tau;
  __syncthreads();                        // thA reads done; unfolds may overwrite
  float h = hv;
  uint4 wr[WR_NREG];
  #pragma unroll 1
  for (int u = 0; u < 6; ++u){
    unsigned* cur = (u & 1) ? thA : thB;
    unsigned* nxt = (u & 1) ? thB : thA;
    const float irec = (u == 0)
        ? matvecR<true >(Wr, cur, wr, wlds, tid)
        : matvecR<false>(Wr, cur, wr, wlds, tid);
    g += (fsig(iin + irec) - g) * ga;
    v += (gs * g * (1.f - v) - gl * v) * va;
    v = fminf(5.f, fmaxf(-5.f, v));
    h = ftanh(v);
    const float hp = __shfl_down(h, 2);
    if (!(tid & 3)) nxt[tid >> 2] = pack2(h, hp);
    __syncthreads();                      // one barrier per unfold
  }
  // layernorm over the 512 outputs (mask duplicate odd lanes)
  const float hm = (tid & 1) ? 0.f : h;
  float s1 = hm, s2 = hm * hm;
  #pragma unroll
  for (int off = 32; off >= 1; off >>= 1){
    s1 += __shfl_down(s1, off);
    s2 += __shfl_down(s2, off);
  }
  const int lane = tid & 63, wid = tid >> 6;
  if (lane == 0){ sred[wid] = s1; sred[16 + wid] = s2; }
  __syncthreads();
  float S1 = 0.f, S2 = 0.f;
  #pragma unroll
  for (int w2 = 0; w2 < 16; ++w2){ S1 += sred[w2]; S2 += sred[16 + w2]; }
  const float m    = S1 * (1.f/512.f);
  const float varr = S2 * (1.f/512.f) - m * m;
  return (h - m) * rsqrtf(varr + 1e-5f) * lw + lb;
}

// ---------- packed-weight offsets (uint4 units) ----------
#define PK_WIN0   0
#define PK_WREC0  16384
#define PK_TA0    49152
#define PK_TB0    98304
#define PK_WIN1   131072
#define PK_WREC1  163840
#define PK_TA1    196608
#define PK_TB1    262144
#define PK_WQ     294912
#define PK_WK     327680
#define PK_WV     360448
#define PK_AO     393216
#define PK_P1     425984
#define PK_P2     442368
#define PK_TOTAL  450560

// ---------- dtype detection (fp32 vs bf16 inputs) ----------
__global__ void detect_kernel(const unsigned* __restrict__ x, int* __restrict__ flag){
  int cnt = 0;
  for (int i = threadIdx.x; i < 4096; i += 256){
    const unsigned e = (x[i] >> 7) & 0xFFu;
    cnt += (e == 0u || e == 0xFFu) ? 1 : 0;
  }
  __shared__ int sh[4];
  #pragma unroll
  for (int off = 32; off >= 1; off >>= 1) cnt += __shfl_down(cnt, off);
  if ((threadIdx.x & 63) == 0) sh[threadIdx.x >> 6] = cnt;
  __syncthreads();
  if (threadIdx.x == 0) *flag = (sh[0] + sh[1] + sh[2] + sh[3] > 4) ? 1 : 0;
}

// ---------- weight packing (dual dtype, [kb2][o][kh] layout) ----------
struct PackDesc {
  const void* src[14];
  long eoff[14];
  int kdiv8[14];
  int lg2n[14];
  int cum[15];
};
__global__ void pack_kernel(PackDesc d, const int* __restrict__ flag,
                            uint4* __restrict__ out){
  const int u = blockIdx.x * 256 + threadIdx.x;
  if (u >= d.cum[14]) return;
  int s = 0;
  #pragma unroll
  for (int i = 1; i < 14; ++i) if (u >= d.cum[i]) s = i;
  const int local   = u - d.cum[s];
  const int ln      = d.lg2n[s];
  const int pairIdx = local >> (ln + 1);
  const int rem     = local & ((2 << ln) - 1);
  const int o       = rem >> 1;
  const int kh      = rem & 1;
  const int kb      = pairIdx * 2 + kh;
  const long base = (long)o * (d.kdiv8[s] * 8) + (long)kb * 8;
  if (*flag){
    const float* sp = (const float*)d.src[s] + d.eoff[s];
    unsigned short h[8];
    #pragma unroll
    for (int i = 0; i < 8; ++i) h[i] = f2b(sp[base + i]);
    uint4 o4;
    o4.x = (unsigned)h[0] | ((unsigned)h[1] << 16);
    o4.y = (unsigned)h[2] | ((unsigned)h[3] << 16);
    o4.z = (unsigned)h[4] | ((unsigned)h[5] << 16);
    o4.w = (unsigned)h[6] | ((unsigned)h[7] << 16);
    out[u] = o4;
  } else {
    const unsigned short* sp = (const unsigned short*)d.src[s] + d.eoff[s];
    out[u] = *(const uint4*)(sp + base);
  }
}

struct VecDesc {
  const void* src[18];
  int n[18];
  int dst[18];
};
__global__ void vec_kernel(VecDesc d, const int* __restrict__ flag,
                           float* __restrict__ pvec){
  const int s = blockIdx.x;
  const int f = *flag;
  for (int i = threadIdx.x; i < d.n[s]; i += blockDim.x)
    pvec[d.dst[s] + i] = f ? ((const float*)d.src[s])[i]
                           : b2f(((const unsigned short*)d.src[s])[i]);
}

// ---------- persistent scan: 1 block per batch row, dynamic LDS ----------
__global__ __launch_bounds__(1024) void scan_kernel(
    const void* __restrict__ xin,
    const uint4* __restrict__ wp,
    const float* __restrict__ pvec,
    const int* __restrict__ flagp,
    unsigned short* __restrict__ seq)
{
  extern __shared__ __align__(16) char smem[];
  unsigned* comb2 = (unsigned*)smem;               // 512 uints
  unsigned* thA   = comb2 + 512;                   // 256
  unsigned* thB   = thA + 256;                     // 256
  float*    sred  = (float*)(thB + 256);           // 32 floats
  uint4*    wlds  = (uint4*)(smem + 4224);         // 9*1024 uint4 = 147456 B

  const int tid = threadIdx.x;
  const int o   = tid >> 1;
  const int b   = blockIdx.x;
  const int isf32 = *flagp;

  float v0 = 0.f, g0 = 0.f, v1 = 0.f, g1 = 0.f;
  const float wb0 = pvec[   0+o], tab0 = pvec[ 512+o], tbb0 = pvec[1024+o];
  const float gl0 = pvec[1536+o], gs0  = pvec[2048+o], lw0  = pvec[2560+o], lb0 = pvec[3072+o];
  const float wb1 = pvec[3584+o], tab1 = pvec[4096+o], tbb1 = pvec[4608+o];
  const float gl1 = pvec[5120+o], gs1  = pvec[5632+o], lw1  = pvec[6144+o], lb1 = pvec[6656+o];

  const uint4* Wi0 = wp + PK_WIN0;  const uint4* Wr0 = wp + PK_WREC0;
  const uint4* Ta0 = wp + PK_TA0;   const uint4* Tb0 = wp + PK_TB0;
  const uint4* Wi1 = wp + PK_WIN1;  const uint4* Wr1 = wp + PK_WREC1;
  const uint4* Ta1 = wp + PK_TA1;   const uint4* Tb1 = wp + PK_TB1;

  #pragma unroll 1
  for (int t = 0; t < 512; ++t){
    if (tid < 128){
      const size_t idx = ((size_t)b*512 + t)*128 + tid;
      if (isf32){
        const float2 xv = ((const float2*)xin)[idx];
        comb2[tid] = pack2(xv.x, xv.y);
      } else {
        comb2[tid] = ((const unsigned*)xin)[idx];
      }
    }
    {
      const float vp = __shfl_down(v0, 2);
      if (!(tid & 3)) comb2[128 + (tid >> 2)] = pack2(v0, vp);
    }
    __syncthreads();
    const float y0 = layer_stepF<256>(v0, g0, Wi0, Wr0, Ta0, Tb0,
                                      wb0, tab0, tbb0, gl0, gs0, lw0, lb0,
                                      comb2, thA, thB, sred, wlds, tid);
    {
      const float yp = __shfl_down(y0, 2);
      const float vp = __shfl_down(v1, 2);
      if (!(tid & 3)){
        comb2[tid >> 2]         = pack2(y0, yp);
        comb2[256 + (tid >> 2)] = pack2(v1, vp);
      }
    }
    __syncthreads();
    const float y1 = layer_stepF<512>(v1, g1, Wi1, Wr1, Ta1, Tb1,
                                      wb1, tab1, tbb1, gl1, gs1, lw1, lb1,
                                      comb2, thA, thB, sred, wlds, tid);
    {
      const float yp = __shfl_down(y1, 2);
      if (!(tid & 3))
        ((unsigned*)seq)[((size_t)b*512 + t)*256 + (tid >> 2)] = pack2(y1, yp);
    }
  }
}

// ---------- Q projection for t = T-1 ----------
__global__ __launch_bounds__(1024) void q_kernel(
    const unsigned short* __restrict__ seq, const uint4* __restrict__ wp,
    const float* __restrict__ pvec, float* __restrict__ qws)
{
  __shared__ __align__(16) unsigned act2[256];
  const int tid = threadIdx.x, b = blockIdx.x;
  if (tid < 256) act2[tid] = ((const unsigned*)seq)[((size_t)(b*512 + 511))*256 + tid];
  __syncthreads();
  const float q = matvecF<512, 512>(wp + PK_WQ, act2, tid) + pvec[7168 + (tid >> 1)];
  if (!(tid & 1)) qws[b*512 + (tid >> 1)] = q;
}

// ---------- scores: one block per (b,t) ----------
__global__ __launch_bounds__(1024) void score_kernel(
    const unsigned short* __restrict__ seq, const uint4* __restrict__ wp,
    const float* __restrict__ pvec, const float* __restrict__ qws,
    float* __restrict__ sws)
{
  __shared__ __align__(16) unsigned act2[256];
  __shared__ float hred[16];
  const int tid = threadIdx.x;
  const int r = blockIdx.x;
  const int b = r >> 9, t = r & 511;
  if (tid < 256) act2[tid] = ((const unsigned*)seq)[(size_t)r*256 + tid];
  __syncthreads();
  const float k = matvecF<512, 512>(wp + PK_WK, act2, tid) + pvec[7680 + (tid >> 1)];
  float part = (tid & 1) ? 0.f : k * qws[b*512 + (tid >> 1)];
  #pragma unroll
  for (int off = 32; off >= 1; off >>= 1) part += __shfl_down(part, off);
  const int lane = tid & 63, wid = tid >> 6;
  if (lane == 0) hred[wid] = part;
  __syncthreads();
  if (tid < 4)
    sws[((size_t)(b*4 + tid))*512 + t] =
        (hred[4*tid] + hred[4*tid+1] + hred[4*tid+2] + hred[4*tid+3])
        * 0.08838834764831845f;
}

// ---------- softmax over t per (b,h); zero-init oacc ----------
__global__ __launch_bounds__(512) void softmax_kernel(
    const float* __restrict__ sws, float* __restrict__ pws,
    float* __restrict__ oacc)
{
  __shared__ float rw[16];
  const int tid = threadIdx.x, bh = blockIdx.x;
  const float s = sws[(size_t)bh*512 + tid];
  float mx = s;
  #pragma unroll
  for (int off = 32; off >= 1; off >>= 1) mx = fmaxf(mx, __shfl_down(mx, off));
  const int lane = tid & 63, wid = tid >> 6;
  if (lane == 0) rw[wid] = mx;
  __syncthreads();
  mx = rw[0];
  #pragma unroll
  for (int w2 = 1; w2 < 8; ++w2) mx = fmaxf(mx, rw[w2]);
  const float e = __expf(s - mx);
  float sm = e;
  #pragma unroll
  for (int off = 32; off >= 1; off >>= 1) sm += __shfl_down(sm, off);
  if (lane == 0) rw[8 + wid] = sm;
  __syncthreads();
  sm = 0.f;
  #pragma unroll
  for (int w2 = 0; w2 < 8; ++w2) sm += rw[8 + w2];
  pws[(size_t)bh*512 + tid] = e / sm;
  if (tid < 128) oacc[(bh >> 2)*512 + (bh & 3)*128 + tid] = 0.f;
}

// ---------- V-accumulate: block = (b, 64-t chunk) ----------
__global__ __launch_bounds__(1024) void vacc_kernel(
    const unsigned short* __restrict__ seq, const uint4* __restrict__ wp,
    const float* __restrict__ pvec, const float* __restrict__ pws,
    float* __restrict__ oacc)
{
  __shared__ __align__(16) unsigned act2[256];
  const int tid = threadIdx.x;
  const int blk = blockIdx.x;
  const int b = blk >> 3, ch = blk & 7;
  float acc = 0.f;
  #pragma unroll 1
  for (int t = ch*64; t < ch*64 + 64; ++t){
    if (tid < 256) act2[tid] = ((const unsigned*)seq)[((size_t)b*512 + t)*256 + tid];
    __syncthreads();
    const float vv = matvecF<512, 512>(wp + PK_WV, act2, tid) + pvec[8192 + (tid >> 1)];
    if (!(tid & 1)) acc += vv * pws[(size_t)(b*4 + (tid >> 8))*512 + t];
    __syncthreads();
  }
  if (!(tid & 1)) atomicAdd(&oacc[b*512 + (tid >> 1)], acc);
}

// ---------- tail ----------
__global__ __launch_bounds__(1024) void final_kernel(
    const float* __restrict__ oacc, const uint4* __restrict__ wp,
    const float* __restrict__ pvec, const int* __restrict__ flagp,
    void* __restrict__ out)
{
  __shared__ __align__(16) unsigned a2[256];
  const int tid = threadIdx.x, b = blockIdx.x;
  const int o   = tid >> 1;
  const int isf32 = *flagp;
  {
    const float x0 = oacc[b*512 + o];
    const float xp = __shfl_down(x0, 2);
    if (!(tid & 3)) a2[tid >> 2] = pack2(x0, xp);
  }
  __syncthreads();
  const float t1 = matvecF<512, 512>(wp + PK_AO, a2, tid) + pvec[8704 + o];
  __syncthreads();
  {
    const float tp = __shfl_down(t1, 2);
    if (!(tid & 3)) a2[tid >> 2] = pack2(t1, tp);
  }
  __syncthreads();
  float t2 = matvecF<512, 256>(wp + PK_P1, a2, tid);
  if (tid < 512) t2 = fmaxf(0.f, t2 + pvec[9216 + o]);
  __syncthreads();
  {
    const float tp = __shfl_down(t2, 2);
    if (tid < 512 && !(tid & 3)) a2[tid >> 2] = pack2(t2, tp);
  }
  __syncthreads();
  const float r = matvecF<256, 256>(wp + PK_P2, a2, tid);
  if (tid < 512 && !(tid & 1)){
    const float rr = r + pvec[9472 + o];
    if (isf32) ((float*)out)[b*256 + o] = rr;
    else       ((unsigned short*)out)[b*256 + o] = f2b(rr);
  }
}

// ---------- fallback if ws too small ----------
__global__ void zero_kernel(unsigned* __restrict__ p, int n){
  const int i = blockIdx.x * 1024 + threadIdx.x;
  if (i < n) p[i] = 0;
}

// ============================================================
#define SCAN_SMEM 151680   // 4224 header + 9*1024*16 Wrec LDS cache

extern "C" void kernel_launch(void* const* d_in, const int* in_sizes, int n_in,
                              void* d_out, int out_size, void* d_ws, size_t ws_size,
                              hipStream_t stream)
{
  (void)in_sizes; (void)n_in; (void)out_size;

  if (ws_size < ((size_t)44 << 20)){
    zero_kernel<<<8, 1024, 0, stream>>>((unsigned*)d_out, 8192);
    return;
  }

  static bool attr_set = false;
  if (!attr_set){
    hipFuncSetAttribute((const void*)scan_kernel,
                        hipFuncAttributeMaxDynamicSharedMemorySize, SCAN_SMEM);
    attr_set = true;
  }

  char* ws = (char*)d_ws;
  int*            flag   = (int*)ws;
  float*          pvec   = (float*)(ws + 4096);
  uint4*          packed = (uint4*)(ws + 65536);
  unsigned short* seq    = (unsigned short*)(ws + ((size_t)8 << 20));
  float*          sws    = (float*)(ws + ((size_t)42 << 20));
  float*          pws    = (float*)(ws + ((size_t)42 << 20) + 524288);
  float*          qws    = (float*)(ws + ((size_t)42 << 20) + 2*524288);
  float*          oacc   = (float*)(ws + ((size_t)42 << 20) + 2*524288 + 131072);

  detect_kernel<<<1, 256, 0, stream>>>((const unsigned*)d_in[0], flag);

  PackDesc pd;
  const void* msrc[14] = {
    d_in[1], d_in[3], d_in[4], d_in[6],
    d_in[12], d_in[14], d_in[15], d_in[17],
    d_in[23], d_in[23], d_in[23],
    d_in[25], d_in[27], d_in[29]
  };
  const long eoff[14] = {0,0,0,0, 0,0,0,0, 0, 262144, 524288, 0, 0, 0};
  const int kk8[14]  = {32,64,96,64, 64,64,128,64, 64,64,64, 64, 64, 32};
  const int ln2[14]  = {9,9,9,9, 9,9,9,9, 9,9,9, 9, 8, 8};
  const int cum[15]  = {0,16384,49152,98304,131072,163840,196608,262144,
                        294912,327680,360448,393216,425984,442368,450560};
  for (int i = 0; i < 14; ++i){
    pd.src[i]=msrc[i]; pd.eoff[i]=eoff[i]; pd.kdiv8[i]=kk8[i]; pd.lg2n[i]=ln2[i];
  }
  for (int i = 0; i < 15; ++i) pd.cum[i] = cum[i];
  pack_kernel<<<(PK_TOTAL + 255)/256, 256, 0, stream>>>(pd, flag, packed);

  VecDesc vd;
  const void* vsrc[18] = {
    d_in[2], d_in[5], d_in[7], d_in[8], d_in[9], d_in[10], d_in[11],
    d_in[13], d_in[16], d_in[18], d_in[19], d_in[20], d_in[21], d_in[22],
    d_in[24], d_in[26], d_in[28], d_in[30]
  };
  const int vn[18]  = {512,512,512,512,512,512,512, 512,512,512,512,512,512,512,
                       1536,512,256,256};
  const int vds[18] = {0,512,1024,1536,2048,2560,3072,
                       3584,4096,4608,5120,5632,6144,6656,
                       7168,8704,9216,9472};
  for (int i = 0; i < 18; ++i){ vd.src[i]=vsrc[i]; vd.n[i]=vn[i]; vd.dst[i]=vds[i]; }
  vec_kernel<<<18, 512, 0, stream>>>(vd, flag, pvec);

  scan_kernel<<<64, 1024, SCAN_SMEM, stream>>>(d_in[0], packed, pvec, flag, seq);
  q_kernel<<<64, 1024, 0, stream>>>(seq, packed, pvec, qws);
  score_kernel<<<64*512, 1024, 0, stream>>>(seq, packed, pvec, qws, sws);
  softmax_kernel<<<256, 512, 0, stream>>>(sws, pws, oacc);
  vacc_kernel<<<512, 1024, 0, stream>>>(seq, packed, pvec, pws, oacc);
  final_kernel<<<64, 1024, 0, stream>>>(oacc, packed, pvec, flag, d_out);
}

// Round 6
// 72561.572 us; speedup vs baseline: 1.0016x; 1.0016x over previous
//
#include <hip/hip_runtime.h>
#include <stdint.h>

// ============================================================
// AdaptiveLNN on MI355X, round 5: round-4 Wrec reg+LDS cache with the
// register-spill fixed. __launch_bounds__(1024,4) raises the VGPR cap
// to 128 so the 12-uint4 register cache stays in VGPRs (r4 spilled to
// scratch: VGPR_Count=64, WRITE_SIZE 10x, FETCH +8GB).
// Wrec slices: [0,12) VGPR, [12,21) LDS (147KB dyn), [21,32) streamed.
// Per-CU stream: 9.9 -> 6.45 MB/step.
// ============================================================

__device__ __forceinline__ float b2f(unsigned short s){
  union { unsigned i; float f; } c; c.i = ((unsigned)s) << 16; return c.f;
}
__device__ __forceinline__ unsigned short f2b(float f){
  union { unsigned i; float f; } c; c.f = f;
  unsigned r = c.i + 0x7fffu + ((c.i >> 16) & 1u);
  return (unsigned short)(r >> 16);
}
__device__ __forceinline__ unsigned pack2(float a, float b){
  return (unsigned)f2b(a) | ((unsigned)f2b(b) << 16);
}
__device__ __forceinline__ float fsig(float x){ return 1.f/(1.f+__expf(-x)); }
__device__ __forceinline__ float ftanh(float x){ return 1.f - 2.f/(__expf(2.f*x)+1.f); }

#if __has_builtin(__builtin_amdgcn_fdot2_f32_bf16)
typedef __bf16 bf16x2_t __attribute__((ext_vector_type(2)));
__device__ __forceinline__ float dot2(unsigned w, unsigned a, float acc){
  union U { unsigned u; bf16x2_t v; };
  U cw; cw.u = w; U ca; ca.u = a;
  return __builtin_amdgcn_fdot2_f32_bf16(cw.v, ca.v, acc, false);
}
#else
__device__ __forceinline__ float dot2(unsigned w, unsigned a, float acc){
  asm("v_dot2_f32_bf16 %0, %1, %2, %0" : "+v"(acc) : "v"(w), "v"(a));
  return acc;
}
#endif

// ---------- streaming full-dot matvec (lane-pair k-split) ----------
template<int K, int NOUT>
__device__ __forceinline__ float matvecF(const uint4* __restrict__ w,
                                         const unsigned* __restrict__ act2,
                                         int tid){
  constexpr int NI = K / 16;
  float acc0 = 0.f, acc1 = 0.f;
  const uint4* a4 = (const uint4*)act2;
  const int kh = tid & 1;
  if (tid < 2*NOUT){
    #pragma unroll 8
    for (int i = 0; i < NI; ++i){
      const uint4 wv = w[(size_t)i*(2*NOUT) + tid];
      const uint4 a  = a4[2*i + kh];
      acc0 = dot2(wv.x, a.x, acc0);
      acc0 = dot2(wv.y, a.y, acc0);
      acc1 = dot2(wv.z, a.z, acc1);
      acc1 = dot2(wv.w, a.w, acc1);
    }
  }
  float acc = acc0 + acc1;
  acc += __shfl_xor(acc, 1);
  return acc;
}

// ---------- cached Wrec matvec (K=512, NOUT=512, 1024 threads) ----------
#define WR_NREG 12
#define WR_NLDS 9
template<bool FILL>
__device__ __forceinline__ float matvecR(const uint4* __restrict__ w,
                                         const unsigned* __restrict__ act2,
                                         uint4 (&wr)[WR_NREG],
                                         uint4* __restrict__ wlds,
                                         int tid){
  float acc0 = 0.f, acc1 = 0.f;
  const uint4* a4 = (const uint4*)act2;
  const int kh = tid & 1;
  #pragma unroll
  for (int i = 0; i < WR_NREG; ++i){
    if (FILL) wr[i] = w[(size_t)i*1024 + tid];
    const uint4 a = a4[2*i + kh];
    acc0 = dot2(wr[i].x, a.x, acc0);
    acc0 = dot2(wr[i].y, a.y, acc0);
    acc1 = dot2(wr[i].z, a.z, acc1);
    acc1 = dot2(wr[i].w, a.w, acc1);
  }
  #pragma unroll
  for (int i = WR_NREG; i < WR_NREG + WR_NLDS; ++i){
    uint4 wv;
    if (FILL){ wv = w[(size_t)i*1024 + tid]; wlds[(i - WR_NREG)*1024 + tid] = wv; }
    else     { wv = wlds[(i - WR_NREG)*1024 + tid]; }
    const uint4 a = a4[2*i + kh];
    acc0 = dot2(wv.x, a.x, acc0);
    acc0 = dot2(wv.y, a.y, acc0);
    acc1 = dot2(wv.z, a.z, acc1);
    acc1 = dot2(wv.w, a.w, acc1);
  }
  #pragma unroll
  for (int i = WR_NREG + WR_NLDS; i < 32; ++i){
    const uint4 wv = w[(size_t)i*1024 + tid];
    const uint4 a  = a4[2*i + kh];
    acc0 = dot2(wv.x, a.x, acc0);
    acc0 = dot2(wv.y, a.y, acc0);
    acc1 = dot2(wv.z, a.z, acc1);
    acc1 = dot2(wv.w, a.w, acc1);
  }
  float acc = acc0 + acc1;
  acc += __shfl_xor(acc, 1);
  return acc;
}

// ---------- one LTC layer, one timestep (scan only; cached Wrec) ----------
template<int FIN>
__device__ __forceinline__ float layer_stepF(
    float& v, float& g,
    const uint4* Wi, const uint4* Wr, const uint4* Ta, const uint4* Tb,
    float wb, float tab, float tbb, float gl, float gs, float lw, float lb,
    unsigned* comb2, unsigned* thA, unsigned* thB, float* sred,
    uint4* wlds, int tid)
{
  float tauh = matvecF<FIN+512, 512>(Ta, comb2, tid);
  float iin  = matvecF<FIN,     512>(Wi, comb2, tid) + wb;
  tauh = ftanh(tauh + tab);
  float hv = ftanh(v);
  {
    const float tp = __shfl_down(tauh, 2);
    const float hp = __shfl_down(hv, 2);
    if (!(tid & 3)){ thA[tid >> 2] = pack2(tauh, tp); thB[tid >> 2] = pack2(hv, hp); }
  }
  __syncthreads();                        // thA (tau_h), thB (tanh v) ready
  float tau = matvecF<512, 512>(Tb, thA, tid);
  tau = 0.1f + 9.9f * fsig(tau + tbb);
  const float ga = 0.2f / tau;
  const float va = 0.1f / tau;
  __syncthreads();                        // thA reads done; unfolds may overwrite
  float h = hv;
  uint4 wr[WR_NREG];
  #pragma unroll 1
  for (int u = 0; u < 6; ++u){
    unsigned* cur = (u & 1) ? thA : thB;
    unsigned* nxt = (u & 1) ? thB : thA;
    const float irec = (u == 0)
        ? matvecR<true >(Wr, cur, wr, wlds, tid)
        : matvecR<false>(Wr, cur, wr, wlds, tid);
    g += (fsig(iin + irec) - g) * ga;
    v += (gs * g * (1.f - v) - gl * v) * va;
    v = fminf(5.f, fmaxf(-5.f, v));
    h = ftanh(v);
    const float hp = __shfl_down(h, 2);
    if (!(tid & 3)) nxt[tid >> 2] = pack2(h, hp);
    __syncthreads();                      // one barrier per unfold
  }
  // layernorm over 512 outputs (mask duplicate odd lanes)
  const float hm = (tid & 1) ? 0.f : h;
  float s1 = hm, s2 = hm * hm;
  #pragma unroll
  for (int off = 32; off >= 1; off >>= 1){
    s1 += __shfl_down(s1, off);
    s2 += __shfl_down(s2, off);
  }
  const int lane = tid & 63, wid = tid >> 6;
  if (lane == 0){ sred[wid] = s1; sred[16 + wid] = s2; }
  __syncthreads();
  float S1 = 0.f, S2 = 0.f;
  #pragma unroll
  for (int w2 = 0; w2 < 16; ++w2){ S1 += sred[w2]; S2 += sred[16 + w2]; }
  const float m    = S1 * (1.f/512.f);
  const float varr = S2 * (1.f/512.f) - m * m;
  return (h - m) * rsqrtf(varr + 1e-5f) * lw + lb;
}

// ---------- packed-weight offsets (uint4 units) ----------
#define PK_WIN0   0
#define PK_WREC0  16384
#define PK_TA0    49152
#define PK_TB0    98304
#define PK_WIN1   131072
#define PK_WREC1  163840
#define PK_TA1    196608
#define PK_TB1    262144
#define PK_WQ     294912
#define PK_WK     327680
#define PK_WV     360448
#define PK_AO     393216
#define PK_P1     425984
#define PK_P2     442368
#define PK_TOTAL  450560

// ---------- dtype detection (fp32 vs bf16 inputs) ----------
__global__ void detect_kernel(const unsigned* __restrict__ x, int* __restrict__ flag){
  int cnt = 0;
  for (int i = threadIdx.x; i < 4096; i += 256){
    const unsigned e = (x[i] >> 7) & 0xFFu;
    cnt += (e == 0u || e == 0xFFu) ? 1 : 0;
  }
  __shared__ int sh[4];
  #pragma unroll
  for (int off = 32; off >= 1; off >>= 1) cnt += __shfl_down(cnt, off);
  if ((threadIdx.x & 63) == 0) sh[threadIdx.x >> 6] = cnt;
  __syncthreads();
  if (threadIdx.x == 0) *flag = (sh[0] + sh[1] + sh[2] + sh[3] > 4) ? 1 : 0;
}

// ---------- weight packing (dual dtype, [kb2][o][kh] layout) ----------
struct PackDesc {
  const void* src[14];
  long eoff[14];
  int kdiv8[14];
  int lg2n[14];
  int cum[15];
};
__global__ void pack_kernel(PackDesc d, const int* __restrict__ flag,
                            uint4* __restrict__ out){
  const int u = blockIdx.x * 256 + threadIdx.x;
  if (u >= d.cum[14]) return;
  int s = 0;
  #pragma unroll
  for (int i = 1; i < 14; ++i) if (u >= d.cum[i]) s = i;
  const int local   = u - d.cum[s];
  const int ln      = d.lg2n[s];
  const int pairIdx = local >> (ln + 1);
  const int rem     = local & ((2 << ln) - 1);
  const int o       = rem >> 1;
  const int kh      = rem & 1;
  const int kb      = pairIdx * 2 + kh;
  const long base = (long)o * (d.kdiv8[s] * 8) + (long)kb * 8;
  if (*flag){
    const float* sp = (const float*)d.src[s] + d.eoff[s];
    unsigned short h[8];
    #pragma unroll
    for (int i = 0; i < 8; ++i) h[i] = f2b(sp[base + i]);
    uint4 o4;
    o4.x = (unsigned)h[0] | ((unsigned)h[1] << 16);
    o4.y = (unsigned)h[2] | ((unsigned)h[3] << 16);
    o4.z = (unsigned)h[4] | ((unsigned)h[5] << 16);
    o4.w = (unsigned)h[6] | ((unsigned)h[7] << 16);
    out[u] = o4;
  } else {
    const unsigned short* sp = (const unsigned short*)d.src[s] + d.eoff[s];
    out[u] = *(const uint4*)(sp + base);
  }
}

struct VecDesc {
  const void* src[18];
  int n[18];
  int dst[18];
};
__global__ void vec_kernel(VecDesc d, const int* __restrict__ flag,
                           float* __restrict__ pvec){
  const int s = blockIdx.x;
  const int f = *flag;
  for (int i = threadIdx.x; i < d.n[s]; i += blockDim.x)
    pvec[d.dst[s] + i] = f ? ((const float*)d.src[s])[i]
                           : b2f(((const unsigned short*)d.src[s])[i]);
}

// ---------- persistent scan: 1 block per batch row, dynamic LDS ----------
// __launch_bounds__(1024, 4): 4 waves/EU -> VGPR cap 128 (room for the
// 48-VGPR Wrec cache; r4's default cap of 64 spilled it to scratch).
__global__ __launch_bounds__(1024, 4) void scan_kernel(
    const void* __restrict__ xin,
    const uint4* __restrict__ wp,
    const float* __restrict__ pvec,
    const int* __restrict__ flagp,
    unsigned short* __restrict__ seq)
{
  extern __shared__ __align__(16) char smem[];
  unsigned* comb2 = (unsigned*)smem;               // 512 uints
  unsigned* thA   = comb2 + 512;                   // 256
  unsigned* thB   = thA + 256;                     // 256
  float*    sred  = (float*)(thB + 256);           // 32 floats
  uint4*    wlds  = (uint4*)(smem + 4224);         // 9*1024 uint4 = 147456 B

  const int tid = threadIdx.x;
  const int o   = tid >> 1;
  const int b   = blockIdx.x;
  const int isf32 = *flagp;

  float v0 = 0.f, g0 = 0.f, v1 = 0.f, g1 = 0.f;
  const float wb0 = pvec[   0+o], tab0 = pvec[ 512+o], tbb0 = pvec[1024+o];
  const float gl0 = pvec[1536+o], gs0  = pvec[2048+o], lw0  = pvec[2560+o], lb0 = pvec[3072+o];
  const float wb1 = pvec[3584+o], tab1 = pvec[4096+o], tbb1 = pvec[4608+o];
  const float gl1 = pvec[5120+o], gs1  = pvec[5632+o], lw1  = pvec[6144+o], lb1 = pvec[6656+o];

  const uint4* Wi0 = wp + PK_WIN0;  const uint4* Wr0 = wp + PK_WREC0;
  const uint4* Ta0 = wp + PK_TA0;   const uint4* Tb0 = wp + PK_TB0;
  const uint4* Wi1 = wp + PK_WIN1;  const uint4* Wr1 = wp + PK_WREC1;
  const uint4* Ta1 = wp + PK_TA1;   const uint4* Tb1 = wp + PK_TB1;

  #pragma unroll 1
  for (int t = 0; t < 512; ++t){
    if (tid < 128){
      const size_t idx = ((size_t)b*512 + t)*128 + tid;
      if (isf32){
        const float2 xv = ((const float2*)xin)[idx];
        comb2[tid] = pack2(xv.x, xv.y);
      } else {
        comb2[tid] = ((const unsigned*)xin)[idx];
      }
    }
    {
      const float vp = __shfl_down(v0, 2);
      if (!(tid & 3)) comb2[128 + (tid >> 2)] = pack2(v0, vp);
    }
    __syncthreads();
    const float y0 = layer_stepF<256>(v0, g0, Wi0, Wr0, Ta0, Tb0,
                                      wb0, tab0, tbb0, gl0, gs0, lw0, lb0,
                                      comb2, thA, thB, sred, wlds, tid);
    {
      const float yp = __shfl_down(y0, 2);
      const float vp = __shfl_down(v1, 2);
      if (!(tid & 3)){
        comb2[tid >> 2]         = pack2(y0, yp);
        comb2[256 + (tid >> 2)] = pack2(v1, vp);
      }
    }
    __syncthreads();
    const float y1 = layer_stepF<512>(v1, g1, Wi1, Wr1, Ta1, Tb1,
                                      wb1, tab1, tbb1, gl1, gs1, lw1, lb1,
                                      comb2, thA, thB, sred, wlds, tid);
    {
      const float yp = __shfl_down(y1, 2);
      if (!(tid & 3))
        ((unsigned*)seq)[((size_t)b*512 + t)*256 + (tid >> 2)] = pack2(y1, yp);
    }
  }
}

// ---------- Q projection for t = T-1 ----------
__global__ __launch_bounds__(1024) void q_kernel(
    const unsigned short* __restrict__ seq, const uint4* __restrict__ wp,
    const float* __restrict__ pvec, float* __restrict__ qws)
{
  __shared__ __align__(16) unsigned act2[256];
  const int tid = threadIdx.x, b = blockIdx.x;
  if (tid < 256) act2[tid] = ((const unsigned*)seq)[((size_t)(b*512 + 511))*256 + tid];
  __syncthreads();
  const float q = matvecF<512, 512>(wp + PK_WQ, act2, tid) + pvec[7168 + (tid >> 1)];
  if (!(tid & 1)) qws[b*512 + (tid >> 1)] = q;
}

// ---------- scores: one block per (b,t) ----------
__global__ __launch_bounds__(1024) void score_kernel(
    const unsigned short* __restrict__ seq, const uint4* __restrict__ wp,
    const float* __restrict__ pvec, const float* __restrict__ qws,
    float* __restrict__ sws)
{
  __shared__ __align__(16) unsigned act2[256];
  __shared__ float hred[16];
  const int tid = threadIdx.x;
  const int r = blockIdx.x;
  const int b = r >> 9, t = r & 511;
  if (tid < 256) act2[tid] = ((const unsigned*)seq)[(size_t)r*256 + tid];
  __syncthreads();
  const float k = matvecF<512, 512>(wp + PK_WK, act2, tid) + pvec[7680 + (tid >> 1)];
  float part = (tid & 1) ? 0.f : k * qws[b*512 + (tid >> 1)];
  #pragma unroll
  for (int off = 32; off >= 1; off >>= 1) part += __shfl_down(part, off);
  const int lane = tid & 63, wid = tid >> 6;
  if (lane == 0) hred[wid] = part;
  __syncthreads();
  if (tid < 4)
    sws[((size_t)(b*4 + tid))*512 + t] =
        (hred[4*tid] + hred[4*tid+1] + hred[4*tid+2] + hred[4*tid+3])
        * 0.08838834764831845f;
}

// ---------- softmax over t per (b,h); zero-init oacc ----------
__global__ __launch_bounds__(512) void softmax_kernel(
    const float* __restrict__ sws, float* __restrict__ pws,
    float* __restrict__ oacc)
{
  __shared__ float rw[16];
  const int tid = threadIdx.x, bh = blockIdx.x;
  const float s = sws[(size_t)bh*512 + tid];
  float mx = s;
  #pragma unroll
  for (int off = 32; off >= 1; off >>= 1) mx = fmaxf(mx, __shfl_down(mx, off));
  const int lane = tid & 63, wid = tid >> 6;
  if (lane == 0) rw[wid] = mx;
  __syncthreads();
  mx = rw[0];
  #pragma unroll
  for (int w2 = 1; w2 < 8; ++w2) mx = fmaxf(mx, rw[w2]);
  const float e = __expf(s - mx);
  float sm = e;
  #pragma unroll
  for (int off = 32; off >= 1; off >>= 1) sm += __shfl_down(sm, off);
  if (lane == 0) rw[8 + wid] = sm;
  __syncthreads();
  sm = 0.f;
  #pragma unroll
  for (int w2 = 0; w2 < 8; ++w2) sm += rw[8 + w2];
  pws[(size_t)bh*512 + tid] = e / sm;
  if (tid < 128) oacc[(bh >> 2)*512 + (bh & 3)*128 + tid] = 0.f;
}

// ---------- V-accumulate: block = (b, 64-t chunk) ----------
__global__ __launch_bounds__(1024) void vacc_kernel(
    const unsigned short* __restrict__ seq, const uint4* __restrict__ wp,
    const float* __restrict__ pvec, const float* __restrict__ pws,
    float* __restrict__ oacc)
{
  __shared__ __align__(16) unsigned act2[256];
  const int tid = threadIdx.x;
  const int blk = blockIdx.x;
  const int b = blk >> 3, ch = blk & 7;
  float acc = 0.f;
  #pragma unroll 1
  for (int t = ch*64; t < ch*64 + 64; ++t){
    if (tid < 256) act2[tid] = ((const unsigned*)seq)[((size_t)b*512 + t)*256 + tid];
    __syncthreads();
    const float vv = matvecF<512, 512>(wp + PK_WV, act2, tid) + pvec[8192 + (tid >> 1)];
    if (!(tid & 1)) acc += vv * pws[(size_t)(b*4 + (tid >> 8))*512 + t];
    __syncthreads();
  }
  if (!(tid & 1)) atomicAdd(&oacc[b*512 + (tid >> 1)], acc);
}

// ---------- tail ----------
__global__ __launch_bounds__(1024) void final_kernel(
    const float* __restrict__ oacc, const uint4* __restrict__ wp,
    const float* __restrict__ pvec, const int* __restrict__ flagp,
    void* __restrict__ out)
{
  __shared__ __align__(16) unsigned a2[256];
  const int tid = threadIdx.x, b = blockIdx.x;
  const int o   = tid >> 1;
  const int isf32 = *flagp;
  {
    const float x0 = oacc[b*512 + o];
    const float xp = __shfl_down(x0, 2);
    if (!(tid & 3)) a2[tid >> 2] = pack2(x0, xp);
  }
  __syncthreads();
  const float t1 = matvecF<512, 512>(wp + PK_AO, a2, tid) + pvec[8704 + o];
  __syncthreads();
  {
    const float tp = __shfl_down(t1, 2);
    if (!(tid & 3)) a2[tid >> 2] = pack2(t1, tp);
  }
  __syncthreads();
  float t2 = matvecF<512, 256>(wp + PK_P1, a2, tid);
  if (tid < 512) t2 = fmaxf(0.f, t2 + pvec[9216 + o]);
  __syncthreads();
  {
    const float tp = __shfl_down(t2, 2);
    if (tid < 512 && !(tid & 3)) a2[tid >> 2] = pack2(t2, tp);
  }
  __syncthreads();
  const float r = matvecF<256, 256>(wp + PK_P2, a2, tid);
  if (tid < 512 && !(tid & 1)){
    const float rr = r + pvec[9472 + o];
    if (isf32) ((float*)out)[b*256 + o] = rr;
    else       ((unsigned short*)out)[b*256 + o] = f2b(rr);
  }
}

// ---------- fallback if ws too small ----------
__global__ void zero_kernel(unsigned* __restrict__ p, int n){
  const int i = blockIdx.x * 1024 + threadIdx.x;
  if (i < n) p[i] = 0;
}

// ============================================================
#define SCAN_SMEM 151680   // 4224 header + 9*1024*16 Wrec LDS cache

extern "C" void kernel_launch(void* const* d_in, const int* in_sizes, int n_in,
                              void* d_out, int out_size, void* d_ws, size_t ws_size,
                              hipStream_t stream)
{
  (void)in_sizes; (void)n_in; (void)out_size;

  if (ws_size < ((size_t)44 << 20)){
    zero_kernel<<<8, 1024, 0, stream>>>((unsigned*)d_out, 8192);
    return;
  }

  // Unconditional (no static guard — kernel_launch must be replay-identical).
  hipFuncSetAttribute((const void*)scan_kernel,
                      hipFuncAttributeMaxDynamicSharedMemorySize, SCAN_SMEM);

  char* ws = (char*)d_ws;
  int*            flag   = (int*)ws;
  float*          pvec   = (float*)(ws + 4096);
  uint4*          packed = (uint4*)(ws + 65536);
  unsigned short* seq    = (unsigned short*)(ws + ((size_t)8 << 20));
  float*          sws    = (float*)(ws + ((size_t)42 << 20));
  float*          pws    = (float*)(ws + ((size_t)42 << 20) + 524288);
  float*          qws    = (float*)(ws + ((size_t)42 << 20) + 2*524288);
  float*          oacc   = (float*)(ws + ((size_t)42 << 20) + 2*524288 + 131072);

  detect_kernel<<<1, 256, 0, stream>>>((const unsigned*)d_in[0], flag);

  PackDesc pd;
  const void* msrc[14] = {
    d_in[1], d_in[3], d_in[4], d_in[6],
    d_in[12], d_in[14], d_in[15], d_in[17],
    d_in[23], d_in[23], d_in[23],
    d_in[25], d_in[27], d_in[29]
  };
  const long eoff[14] = {0,0,0,0, 0,0,0,0, 0, 262144, 524288, 0, 0, 0};
  const int kk8[14]  = {32,64,96,64, 64,64,128,64, 64,64,64, 64, 64, 32};
  const int ln2[14]  = {9,9,9,9, 9,9,9,9, 9,9,9, 9, 8, 8};
  const int cum[15]  = {0,16384,49152,98304,131072,163840,196608,262144,
                        294912,327680,360448,393216,425984,442368,450560};
  for (int i = 0; i < 14; ++i){
    pd.src[i]=msrc[i]; pd.eoff[i]=eoff[i]; pd.kdiv8[i]=kk8[i]; pd.lg2n[i]=ln2[i];
  }
  for (int i = 0; i < 15; ++i) pd.cum[i] = cum[i];
  pack_kernel<<<(PK_TOTAL + 255)/256, 256, 0, stream>>>(pd, flag, packed);

  VecDesc vd;
  const void* vsrc[18] = {
    d_in[2], d_in[5], d_in[7], d_in[8], d_in[9], d_in[10], d_in[11],
    d_in[13], d_in[16], d_in[18], d_in[19], d_in[20], d_in[21], d_in[22],
    d_in[24], d_in[26], d_in[28], d_in[30]
  };
  const int vn[18]  = {512,512,512,512,512,512,512, 512,512,512,512,512,512,512,
                       1536,512,256,256};
  const int vds[18] = {0,512,1024,1536,2048,2560,3072,
                       3584,4096,4608,5120,5632,6144,6656,
                       7168,8704,9216,9472};
  for (int i = 0; i < 18; ++i){ vd.src[i]=vsrc[i]; vd.n[i]=vn[i]; vd.dst[i]=vds[i]; }
  vec_kernel<<<18, 512, 0, stream>>>(vd, flag, pvec);

  scan_kernel<<<64, 1024, SCAN_SMEM, stream>>>(d_in[0], packed, pvec, flag, seq);
  q_kernel<<<64, 1024, 0, stream>>>(seq, packed, pvec, qws);
  score_kernel<<<64*512, 1024, 0, stream>>>(seq, packed, pvec, qws, sws);
  softmax_kernel<<<256, 512, 0, stream>>>(sws, pws, oacc);
  vacc_kernel<<<512, 1024, 0, stream>>>(seq, packed, pvec, pws, oacc);
  final_kernel<<<64, 1024, 0, stream>>>(oacc, packed, pvec, flag, d_out);
}

// Round 7
// 71570.941 us; speedup vs baseline: 1.0154x; 1.0138x over previous
//
#include <hip/hip_runtime.h>
#include <stdint.h>

// ============================================================
// AdaptiveLNN on MI355X, round 6: force the Wrec register cache with
// amdgpu_waves_per_eu(4,4). r5/r6 showed __launch_bounds__(1024,4) does
// NOT raise the backend's VGPR budget (stayed 64 -> wr[12] spilled to
// scratch -> +7.5GB FETCH, +290MB WRITE, 72ms). The clamped attribute
// pins occupancy to exactly 4 waves/EU => 128-VGPR budget.
// Wrec slices: [0,12) VGPR, [12,21) LDS (147KB dyn), [21,32) streamed.
// Per-CU stream: 9.9 -> 6.45 MB/step.
// ============================================================

__device__ __forceinline__ float b2f(unsigned short s){
  union { unsigned i; float f; } c; c.i = ((unsigned)s) << 16; return c.f;
}
__device__ __forceinline__ unsigned short f2b(float f){
  union { unsigned i; float f; } c; c.f = f;
  unsigned r = c.i + 0x7fffu + ((c.i >> 16) & 1u);
  return (unsigned short)(r >> 16);
}
__device__ __forceinline__ unsigned pack2(float a, float b){
  return (unsigned)f2b(a) | ((unsigned)f2b(b) << 16);
}
__device__ __forceinline__ float fsig(float x){ return 1.f/(1.f+__expf(-x)); }
__device__ __forceinline__ float ftanh(float x){ return 1.f - 2.f/(__expf(2.f*x)+1.f); }

#if __has_builtin(__builtin_amdgcn_fdot2_f32_bf16)
typedef __bf16 bf16x2_t __attribute__((ext_vector_type(2)));
__device__ __forceinline__ float dot2(unsigned w, unsigned a, float acc){
  union U { unsigned u; bf16x2_t v; };
  U cw; cw.u = w; U ca; ca.u = a;
  return __builtin_amdgcn_fdot2_f32_bf16(cw.v, ca.v, acc, false);
}
#else
__device__ __forceinline__ float dot2(unsigned w, unsigned a, float acc){
  asm("v_dot2_f32_bf16 %0, %1, %2, %0" : "+v"(acc) : "v"(w), "v"(a));
  return acc;
}
#endif

// ---------- streaming full-dot matvec (lane-pair k-split) ----------
template<int K, int NOUT>
__device__ __forceinline__ float matvecF(const uint4* __restrict__ w,
                                         const unsigned* __restrict__ act2,
                                         int tid){
  constexpr int NI = K / 16;
  float acc0 = 0.f, acc1 = 0.f;
  const uint4* a4 = (const uint4*)act2;
  const int kh = tid & 1;
  if (tid < 2*NOUT){
    #pragma unroll 8
    for (int i = 0; i < NI; ++i){
      const uint4 wv = w[(size_t)i*(2*NOUT) + tid];
      const uint4 a  = a4[2*i + kh];
      acc0 = dot2(wv.x, a.x, acc0);
      acc0 = dot2(wv.y, a.y, acc0);
      acc1 = dot2(wv.z, a.z, acc1);
      acc1 = dot2(wv.w, a.w, acc1);
    }
  }
  float acc = acc0 + acc1;
  acc += __shfl_xor(acc, 1);
  return acc;
}

// ---------- cached Wrec matvec (K=512, NOUT=512, 1024 threads) ----------
#define WR_NREG 12
#define WR_NLDS 9
template<bool FILL>
__device__ __forceinline__ float matvecR(const uint4* __restrict__ w,
                                         const unsigned* __restrict__ act2,
                                         uint4 (&wr)[WR_NREG],
                                         uint4* __restrict__ wlds,
                                         int tid){
  float acc0 = 0.f, acc1 = 0.f;
  const uint4* a4 = (const uint4*)act2;
  const int kh = tid & 1;
  #pragma unroll
  for (int i = 0; i < WR_NREG; ++i){
    if (FILL) wr[i] = w[(size_t)i*1024 + tid];
    const uint4 a = a4[2*i + kh];
    acc0 = dot2(wr[i].x, a.x, acc0);
    acc0 = dot2(wr[i].y, a.y, acc0);
    acc1 = dot2(wr[i].z, a.z, acc1);
    acc1 = dot2(wr[i].w, a.w, acc1);
  }
  #pragma unroll
  for (int i = WR_NREG; i < WR_NREG + WR_NLDS; ++i){
    uint4 wv;
    if (FILL){ wv = w[(size_t)i*1024 + tid]; wlds[(i - WR_NREG)*1024 + tid] = wv; }
    else     { wv = wlds[(i - WR_NREG)*1024 + tid]; }
    const uint4 a = a4[2*i + kh];
    acc0 = dot2(wv.x, a.x, acc0);
    acc0 = dot2(wv.y, a.y, acc0);
    acc1 = dot2(wv.z, a.z, acc1);
    acc1 = dot2(wv.w, a.w, acc1);
  }
  #pragma unroll
  for (int i = WR_NREG + WR_NLDS; i < 32; ++i){
    const uint4 wv = w[(size_t)i*1024 + tid];
    const uint4 a  = a4[2*i + kh];
    acc0 = dot2(wv.x, a.x, acc0);
    acc0 = dot2(wv.y, a.y, acc0);
    acc1 = dot2(wv.z, a.z, acc1);
    acc1 = dot2(wv.w, a.w, acc1);
  }
  float acc = acc0 + acc1;
  acc += __shfl_xor(acc, 1);
  return acc;
}

// ---------- one LTC layer, one timestep (scan only; cached Wrec) ----------
template<int FIN>
__device__ __forceinline__ float layer_stepF(
    float& v, float& g,
    const uint4* Wi, const uint4* Wr, const uint4* Ta, const uint4* Tb,
    float wb, float tab, float tbb, float gl, float gs, float lw, float lb,
    unsigned* comb2, unsigned* thA, unsigned* thB, float* sred,
    uint4* wlds, int tid)
{
  float tauh = matvecF<FIN+512, 512>(Ta, comb2, tid);
  float iin  = matvecF<FIN,     512>(Wi, comb2, tid) + wb;
  tauh = ftanh(tauh + tab);
  float hv = ftanh(v);
  {
    const float tp = __shfl_down(tauh, 2);
    const float hp = __shfl_down(hv, 2);
    if (!(tid & 3)){ thA[tid >> 2] = pack2(tauh, tp); thB[tid >> 2] = pack2(hv, hp); }
  }
  __syncthreads();                        // thA (tau_h), thB (tanh v) ready
  float tau = matvecF<512, 512>(Tb, thA, tid);
  tau = 0.1f + 9.9f * fsig(tau + tbb);
  const float ga = 0.2f / tau;
  const float va = 0.1f / tau;
  __syncthreads();                        // thA reads done; unfolds may overwrite
  float h = hv;
  uint4 wr[WR_NREG];
  #pragma unroll 1
  for (int u = 0; u < 6; ++u){
    unsigned* cur = (u & 1) ? thA : thB;
    unsigned* nxt = (u & 1) ? thB : thA;
    const float irec = (u == 0)
        ? matvecR<true >(Wr, cur, wr, wlds, tid)
        : matvecR<false>(Wr, cur, wr, wlds, tid);
    g += (fsig(iin + irec) - g) * ga;
    v += (gs * g * (1.f - v) - gl * v) * va;
    v = fminf(5.f, fmaxf(-5.f, v));
    h = ftanh(v);
    const float hp = __shfl_down(h, 2);
    if (!(tid & 3)) nxt[tid >> 2] = pack2(h, hp);
    __syncthreads();                      // one barrier per unfold
  }
  // layernorm over 512 outputs (mask duplicate odd lanes)
  const float hm = (tid & 1) ? 0.f : h;
  float s1 = hm, s2 = hm * hm;
  #pragma unroll
  for (int off = 32; off >= 1; off >>= 1){
    s1 += __shfl_down(s1, off);
    s2 += __shfl_down(s2, off);
  }
  const int lane = tid & 63, wid = tid >> 6;
  if (lane == 0){ sred[wid] = s1; sred[16 + wid] = s2; }
  __syncthreads();
  float S1 = 0.f, S2 = 0.f;
  #pragma unroll
  for (int w2 = 0; w2 < 16; ++w2){ S1 += sred[w2]; S2 += sred[16 + w2]; }
  const float m    = S1 * (1.f/512.f);
  const float varr = S2 * (1.f/512.f) - m * m;
  return (h - m) * rsqrtf(varr + 1e-5f) * lw + lb;
}

// ---------- packed-weight offsets (uint4 units) ----------
#define PK_WIN0   0
#define PK_WREC0  16384
#define PK_TA0    49152
#define PK_TB0    98304
#define PK_WIN1   131072
#define PK_WREC1  163840
#define PK_TA1    196608
#define PK_TB1    262144
#define PK_WQ     294912
#define PK_WK     327680
#define PK_WV     360448
#define PK_AO     393216
#define PK_P1     425984
#define PK_P2     442368
#define PK_TOTAL  450560

// ---------- dtype detection (fp32 vs bf16 inputs) ----------
__global__ void detect_kernel(const unsigned* __restrict__ x, int* __restrict__ flag){
  int cnt = 0;
  for (int i = threadIdx.x; i < 4096; i += 256){
    const unsigned e = (x[i] >> 7) & 0xFFu;
    cnt += (e == 0u || e == 0xFFu) ? 1 : 0;
  }
  __shared__ int sh[4];
  #pragma unroll
  for (int off = 32; off >= 1; off >>= 1) cnt += __shfl_down(cnt, off);
  if ((threadIdx.x & 63) == 0) sh[threadIdx.x >> 6] = cnt;
  __syncthreads();
  if (threadIdx.x == 0) *flag = (sh[0] + sh[1] + sh[2] + sh[3] > 4) ? 1 : 0;
}

// ---------- weight packing (dual dtype, [kb2][o][kh] layout) ----------
struct PackDesc {
  const void* src[14];
  long eoff[14];
  int kdiv8[14];
  int lg2n[14];
  int cum[15];
};
__global__ void pack_kernel(PackDesc d, const int* __restrict__ flag,
                            uint4* __restrict__ out){
  const int u = blockIdx.x * 256 + threadIdx.x;
  if (u >= d.cum[14]) return;
  int s = 0;
  #pragma unroll
  for (int i = 1; i < 14; ++i) if (u >= d.cum[i]) s = i;
  const int local   = u - d.cum[s];
  const int ln      = d.lg2n[s];
  const int pairIdx = local >> (ln + 1);
  const int rem     = local & ((2 << ln) - 1);
  const int o       = rem >> 1;
  const int kh      = rem & 1;
  const int kb      = pairIdx * 2 + kh;
  const long base = (long)o * (d.kdiv8[s] * 8) + (long)kb * 8;
  if (*flag){
    const float* sp = (const float*)d.src[s] + d.eoff[s];
    unsigned short h[8];
    #pragma unroll
    for (int i = 0; i < 8; ++i) h[i] = f2b(sp[base + i]);
    uint4 o4;
    o4.x = (unsigned)h[0] | ((unsigned)h[1] << 16);
    o4.y = (unsigned)h[2] | ((unsigned)h[3] << 16);
    o4.z = (unsigned)h[4] | ((unsigned)h[5] << 16);
    o4.w = (unsigned)h[6] | ((unsigned)h[7] << 16);
    out[u] = o4;
  } else {
    const unsigned short* sp = (const unsigned short*)d.src[s] + d.eoff[s];
    out[u] = *(const uint4*)(sp + base);
  }
}

struct VecDesc {
  const void* src[18];
  int n[18];
  int dst[18];
};
__global__ void vec_kernel(VecDesc d, const int* __restrict__ flag,
                           float* __restrict__ pvec){
  const int s = blockIdx.x;
  const int f = *flag;
  for (int i = threadIdx.x; i < d.n[s]; i += blockDim.x)
    pvec[d.dst[s] + i] = f ? ((const float*)d.src[s])[i]
                           : b2f(((const unsigned short*)d.src[s])[i]);
}

// ---------- persistent scan: 1 block per batch row, dynamic LDS ----------
// amdgpu_waves_per_eu(4,4): clamp occupancy to exactly 4 waves/EU so the
// register budget is 512/4 = 128 VGPRs (launch_bounds min alone was
// ignored by the allocator: VGPR stayed 64 and wr[] spilled, r5/r6).
__global__ __launch_bounds__(1024)
__attribute__((amdgpu_waves_per_eu(4, 4)))
void scan_kernel(
    const void* __restrict__ xin,
    const uint4* __restrict__ wp,
    const float* __restrict__ pvec,
    const int* __restrict__ flagp,
    unsigned short* __restrict__ seq)
{
  extern __shared__ __align__(16) char smem[];
  unsigned* comb2 = (unsigned*)smem;               // 512 uints
  unsigned* thA   = comb2 + 512;                   // 256
  unsigned* thB   = thA + 256;                     // 256
  float*    sred  = (float*)(thB + 256);           // 32 floats
  uint4*    wlds  = (uint4*)(smem + 4224);         // 9*1024 uint4 = 147456 B

  const int tid = threadIdx.x;
  const int o   = tid >> 1;
  const int b   = blockIdx.x;
  const int isf32 = *flagp;

  float v0 = 0.f, g0 = 0.f, v1 = 0.f, g1 = 0.f;
  const float wb0 = pvec[   0+o], tab0 = pvec[ 512+o], tbb0 = pvec[1024+o];
  const float gl0 = pvec[1536+o], gs0  = pvec[2048+o], lw0  = pvec[2560+o], lb0 = pvec[3072+o];
  const float wb1 = pvec[3584+o], tab1 = pvec[4096+o], tbb1 = pvec[4608+o];
  const float gl1 = pvec[5120+o], gs1  = pvec[5632+o], lw1  = pvec[6144+o], lb1 = pvec[6656+o];

  const uint4* Wi0 = wp + PK_WIN0;  const uint4* Wr0 = wp + PK_WREC0;
  const uint4* Ta0 = wp + PK_TA0;   const uint4* Tb0 = wp + PK_TB0;
  const uint4* Wi1 = wp + PK_WIN1;  const uint4* Wr1 = wp + PK_WREC1;
  const uint4* Ta1 = wp + PK_TA1;   const uint4* Tb1 = wp + PK_TB1;

  #pragma unroll 1
  for (int t = 0; t < 512; ++t){
    if (tid < 128){
      const size_t idx = ((size_t)b*512 + t)*128 + tid;
      if (isf32){
        const float2 xv = ((const float2*)xin)[idx];
        comb2[tid] = pack2(xv.x, xv.y);
      } else {
        comb2[tid] = ((const unsigned*)xin)[idx];
      }
    }
    {
      const float vp = __shfl_down(v0, 2);
      if (!(tid & 3)) comb2[128 + (tid >> 2)] = pack2(v0, vp);
    }
    __syncthreads();
    const float y0 = layer_stepF<256>(v0, g0, Wi0, Wr0, Ta0, Tb0,
                                      wb0, tab0, tbb0, gl0, gs0, lw0, lb0,
                                      comb2, thA, thB, sred, wlds, tid);
    {
      const float yp = __shfl_down(y0, 2);
      const float vp = __shfl_down(v1, 2);
      if (!(tid & 3)){
        comb2[tid >> 2]         = pack2(y0, yp);
        comb2[256 + (tid >> 2)] = pack2(v1, vp);
      }
    }
    __syncthreads();
    const float y1 = layer_stepF<512>(v1, g1, Wi1, Wr1, Ta1, Tb1,
                                      wb1, tab1, tbb1, gl1, gs1, lw1, lb1,
                                      comb2, thA, thB, sred, wlds, tid);
    {
      const float yp = __shfl_down(y1, 2);
      if (!(tid & 3))
        ((unsigned*)seq)[((size_t)b*512 + t)*256 + (tid >> 2)] = pack2(y1, yp);
    }
  }
}

// ---------- Q projection for t = T-1 ----------
__global__ __launch_bounds__(1024) void q_kernel(
    const unsigned short* __restrict__ seq, const uint4* __restrict__ wp,
    const float* __restrict__ pvec, float* __restrict__ qws)
{
  __shared__ __align__(16) unsigned act2[256];
  const int tid = threadIdx.x, b = blockIdx.x;
  if (tid < 256) act2[tid] = ((const unsigned*)seq)[((size_t)(b*512 + 511))*256 + tid];
  __syncthreads();
  const float q = matvecF<512, 512>(wp + PK_WQ, act2, tid) + pvec[7168 + (tid >> 1)];
  if (!(tid & 1)) qws[b*512 + (tid >> 1)] = q;
}

// ---------- scores: one block per (b,t) ----------
__global__ __launch_bounds__(1024) void score_kernel(
    const unsigned short* __restrict__ seq, const uint4* __restrict__ wp,
    const float* __restrict__ pvec, const float* __restrict__ qws,
    float* __restrict__ sws)
{
  __shared__ __align__(16) unsigned act2[256];
  __shared__ float hred[16];
  const int tid = threadIdx.x;
  const int r = blockIdx.x;
  const int b = r >> 9, t = r & 511;
  if (tid < 256) act2[tid] = ((const unsigned*)seq)[(size_t)r*256 + tid];
  __syncthreads();
  const float k = matvecF<512, 512>(wp + PK_WK, act2, tid) + pvec[7680 + (tid >> 1)];
  float part = (tid & 1) ? 0.f : k * qws[b*512 + (tid >> 1)];
  #pragma unroll
  for (int off = 32; off >= 1; off >>= 1) part += __shfl_down(part, off);
  const int lane = tid & 63, wid = tid >> 6;
  if (lane == 0) hred[wid] = part;
  __syncthreads();
  if (tid < 4)
    sws[((size_t)(b*4 + tid))*512 + t] =
        (hred[4*tid] + hred[4*tid+1] + hred[4*tid+2] + hred[4*tid+3])
        * 0.08838834764831845f;
}

// ---------- softmax over t per (b,h); zero-init oacc ----------
__global__ __launch_bounds__(512) void softmax_kernel(
    const float* __restrict__ sws, float* __restrict__ pws,
    float* __restrict__ oacc)
{
  __shared__ float rw[16];
  const int tid = threadIdx.x, bh = blockIdx.x;
  const float s = sws[(size_t)bh*512 + tid];
  float mx = s;
  #pragma unroll
  for (int off = 32; off >= 1; off >>= 1) mx = fmaxf(mx, __shfl_down(mx, off));
  const int lane = tid & 63, wid = tid >> 6;
  if (lane == 0) rw[wid] = mx;
  __syncthreads();
  mx = rw[0];
  #pragma unroll
  for (int w2 = 1; w2 < 8; ++w2) mx = fmaxf(mx, rw[w2]);
  const float e = __expf(s - mx);
  float sm = e;
  #pragma unroll
  for (int off = 32; off >= 1; off >>= 1) sm += __shfl_down(sm, off);
  if (lane == 0) rw[8 + wid] = sm;
  __syncthreads();
  sm = 0.f;
  #pragma unroll
  for (int w2 = 0; w2 < 8; ++w2) sm += rw[8 + w2];
  pws[(size_t)bh*512 + tid] = e / sm;
  if (tid < 128) oacc[(bh >> 2)*512 + (bh & 3)*128 + tid] = 0.f;
}

// ---------- V-accumulate: block = (b, 64-t chunk) ----------
__global__ __launch_bounds__(1024) void vacc_kernel(
    const unsigned short* __restrict__ seq, const uint4* __restrict__ wp,
    const float* __restrict__ pvec, const float* __restrict__ pws,
    float* __restrict__ oacc)
{
  __shared__ __align__(16) unsigned act2[256];
  const int tid = threadIdx.x;
  const int blk = blockIdx.x;
  const int b = blk >> 3, ch = blk & 7;
  float acc = 0.f;
  #pragma unroll 1
  for (int t = ch*64; t < ch*64 + 64; ++t){
    if (tid < 256) act2[tid] = ((const unsigned*)seq)[((size_t)b*512 + t)*256 + tid];
    __syncthreads();
    const float vv = matvecF<512, 512>(wp + PK_WV, act2, tid) + pvec[8192 + (tid >> 1)];
    if (!(tid & 1)) acc += vv * pws[(size_t)(b*4 + (tid >> 8))*512 + t];
    __syncthreads();
  }
  if (!(tid & 1)) atomicAdd(&oacc[b*512 + (tid >> 1)], acc);
}

// ---------- tail ----------
__global__ __launch_bounds__(1024) void final_kernel(
    const float* __restrict__ oacc, const uint4* __restrict__ wp,
    const float* __restrict__ pvec, const int* __restrict__ flagp,
    void* __restrict__ out)
{
  __shared__ __align__(16) unsigned a2[256];
  const int tid = threadIdx.x, b = blockIdx.x;
  const int o   = tid >> 1;
  const int isf32 = *flagp;
  {
    const float x0 = oacc[b*512 + o];
    const float xp = __shfl_down(x0, 2);
    if (!(tid & 3)) a2[tid >> 2] = pack2(x0, xp);
  }
  __syncthreads();
  const float t1 = matvecF<512, 512>(wp + PK_AO, a2, tid) + pvec[8704 + o];
  __syncthreads();
  {
    const float tp = __shfl_down(t1, 2);
    if (!(tid & 3)) a2[tid >> 2] = pack2(t1, tp);
  }
  __syncthreads();
  float t2 = matvecF<512, 256>(wp + PK_P1, a2, tid);
  if (tid < 512) t2 = fmaxf(0.f, t2 + pvec[9216 + o]);
  __syncthreads();
  {
    const float tp = __shfl_down(t2, 2);
    if (tid < 512 && !(tid & 3)) a2[tid >> 2] = pack2(t2, tp);
  }
  __syncthreads();
  const float r = matvecF<256, 256>(wp + PK_P2, a2, tid);
  if (tid < 512 && !(tid & 1)){
    const float rr = r + pvec[9472 + o];
    if (isf32) ((float*)out)[b*256 + o] = rr;
    else       ((unsigned short*)out)[b*256 + o] = f2b(rr);
  }
}

// ---------- fallback if ws too small ----------
__global__ void zero_kernel(unsigned* __restrict__ p, int n){
  const int i = blockIdx.x * 1024 + threadIdx.x;
  if (i < n) p[i] = 0;
}

// ============================================================
#define SCAN_SMEM 151680   // 4224 header + 9*1024*16 Wrec LDS cache

extern "C" void kernel_launch(void* const* d_in, const int* in_sizes, int n_in,
                              void* d_out, int out_size, void* d_ws, size_t ws_size,
                              hipStream_t stream)
{
  (void)in_sizes; (void)n_in; (void)out_size;

  if (ws_size < ((size_t)44 << 20)){
    zero_kernel<<<8, 1024, 0, stream>>>((unsigned*)d_out, 8192);
    return;
  }

  hipFuncSetAttribute((const void*)scan_kernel,
                      hipFuncAttributeMaxDynamicSharedMemorySize, SCAN_SMEM);

  char* ws = (char*)d_ws;
  int*            flag   = (int*)ws;
  float*          pvec   = (float*)(ws + 4096);
  uint4*          packed = (uint4*)(ws + 65536);
  unsigned short* seq    = (unsigned short*)(ws + ((size_t)8 << 20));
  float*          sws    = (float*)(ws + ((size_t)42 << 20));
  float*          pws    = (float*)(ws + ((size_t)42 << 20) + 524288);
  float*          qws    = (float*)(ws + ((size_t)42 << 20) + 2*524288);
  float*          oacc   = (float*)(ws + ((size_t)42 << 20) + 2*524288 + 131072);

  detect_kernel<<<1, 256, 0, stream>>>((const unsigned*)d_in[0], flag);

  PackDesc pd;
  const void* msrc[14] = {
    d_in[1], d_in[3], d_in[4], d_in[6],
    d_in[12], d_in[14], d_in[15], d_in[17],
    d_in[23], d_in[23], d_in[23],
    d_in[25], d_in[27], d_in[29]
  };
  const long eoff[14] = {0,0,0,0, 0,0,0,0, 0, 262144, 524288, 0, 0, 0};
  const int kk8[14]  = {32,64,96,64, 64,64,128,64, 64,64,64, 64, 64, 32};
  const int ln2[14]  = {9,9,9,9, 9,9,9,9, 9,9,9, 9, 8, 8};
  const int cum[15]  = {0,16384,49152,98304,131072,163840,196608,262144,
                        294912,327680,360448,393216,425984,442368,450560};
  for (int i = 0; i < 14; ++i){
    pd.src[i]=msrc[i]; pd.eoff[i]=eoff[i]; pd.kdiv8[i]=kk8[i]; pd.lg2n[i]=ln2[i];
  }
  for (int i = 0; i < 15; ++i) pd.cum[i] = cum[i];
  pack_kernel<<<(PK_TOTAL + 255)/256, 256, 0, stream>>>(pd, flag, packed);

  VecDesc vd;
  const void* vsrc[18] = {
    d_in[2], d_in[5], d_in[7], d_in[8], d_in[9], d_in[10], d_in[11],
    d_in[13], d_in[16], d_in[18], d_in[19], d_in[20], d_in[21], d_in[22],
    d_in[24], d_in[26], d_in[28], d_in[30]
  };
  const int vn[18]  = {512,512,512,512,512,512,512, 512,512,512,512,512,512,512,
                       1536,512,256,256};
  const int vds[18] = {0,512,1024,1536,2048,2560,3072,
                       3584,4096,4608,5120,5632,6144,6656,
                       7168,8704,9216,9472};
  for (int i = 0; i < 18; ++i){ vd.src[i]=vsrc[i]; vd.n[i]=vn[i]; vd.dst[i]=vds[i]; }
  vec_kernel<<<18, 512, 0, stream>>>(vd, flag, pvec);

  scan_kernel<<<64, 1024, SCAN_SMEM, stream>>>(d_in[0], packed, pvec, flag, seq);
  q_kernel<<<64, 1024, 0, stream>>>(seq, packed, pvec, qws);
  score_kernel<<<64*512, 1024, 0, stream>>>(seq, packed, pvec, qws, sws);
  softmax_kernel<<<256, 512, 0, stream>>>(sws, pws, oacc);
  vacc_kernel<<<512, 1024, 0, stream>>>(seq, packed, pvec, pws, oacc);
  final_kernel<<<64, 1024, 0, stream>>>(oacc, packed, pvec, flag, d_out);
}

// Round 8
// 34623.203 us; speedup vs baseline: 2.0991x; 2.0671x over previous
//
#include <hip/hip_runtime.h>
#include <stdint.h>

// ============================================================
// AdaptiveLNN on MI355X, round 7: layer-pipelined scan.
// 128 blocks x 512 threads: blocks [0,64) = layer0 ("A"), [64,128) =
// layer1 ("B") one step behind, h0 handed through an 8-deep ring with
// agent-scope atomics. Each block streams only its layer's weights
// (~4 MB/step vs 9.9) + 147KB LDS-resident Wrec slice (thread-private,
// filled once at t=0). 2 outputs/thread + lane-pair k-split cuts LDS
// broadcast instructions ~4x vs r3. No register cache (r4-r7: allocator
// refuses >64 VGPRs for big blocks and spills).
// ============================================================

__device__ __forceinline__ float b2f(unsigned short s){
  union { unsigned i; float f; } c; c.i = ((unsigned)s) << 16; return c.f;
}
__device__ __forceinline__ unsigned short f2b(float f){
  union { unsigned i; float f; } c; c.f = f;
  unsigned r = c.i + 0x7fffu + ((c.i >> 16) & 1u);
  return (unsigned short)(r >> 16);
}
__device__ __forceinline__ unsigned pack2(float a, float b){
  return (unsigned)f2b(a) | ((unsigned)f2b(b) << 16);
}
__device__ __forceinline__ float fsig(float x){ return 1.f/(1.f+__expf(-x)); }
__device__ __forceinline__ float ftanh(float x){ return 1.f - 2.f/(__expf(2.f*x)+1.f); }

#if __has_builtin(__builtin_amdgcn_fdot2_f32_bf16)
typedef __bf16 bf16x2_t __attribute__((ext_vector_type(2)));
__device__ __forceinline__ float dot2(unsigned w, unsigned a, float acc){
  union U { unsigned u; bf16x2_t v; };
  U cw; cw.u = w; U ca; ca.u = a;
  return __builtin_amdgcn_fdot2_f32_bf16(cw.v, ca.v, acc, false);
}
#else
__device__ __forceinline__ float dot2(unsigned w, unsigned a, float acc){
  asm("v_dot2_f32_bf16 %0, %1, %2, %0" : "+v"(acc) : "v"(w), "v"(a));
  return acc;
}
#endif

// ---------- matvec: 512 threads, thread tid: p=tid>>1, kh=tid&1 ----------
// Outputs o_j = j*256+p (j < NJ=NOUT/256). Weight layout:
//   w[(ib*NJ+j)*512 + tid] = uint4 (8 bf16) of row o_j, k-octet (2*ib+kh).
// act2: K/2 packed bf16 pairs (K/8 uint4). Both pair lanes return full dot.
template<int K, int NOUT>
__device__ __forceinline__ void matvec2(const uint4* __restrict__ w,
                                        const unsigned* __restrict__ act2,
                                        int tid, float* out){
  constexpr int NJ = NOUT/256, NIB = K/16;
  const uint4* a4 = (const uint4*)act2;
  const int kh = tid & 1;
  float acc[NJ];
  #pragma unroll
  for (int j = 0; j < NJ; ++j) acc[j] = 0.f;
  #pragma unroll 2
  for (int ib = 0; ib < NIB; ++ib){
    const uint4 a = a4[2*ib + kh];
    #pragma unroll
    for (int j = 0; j < NJ; ++j){
      const uint4 wv = w[(size_t)(ib*NJ + j)*512 + tid];
      acc[j] = dot2(wv.x, a.x, acc[j]);
      acc[j] = dot2(wv.y, a.y, acc[j]);
      acc[j] = dot2(wv.z, a.z, acc[j]);
      acc[j] = dot2(wv.w, a.w, acc[j]);
    }
  }
  #pragma unroll
  for (int j = 0; j < NJ; ++j){
    float s = acc[j];
    s += __shfl_xor(s, 1);
    out[j] = s;
  }
}

// ---------- Wrec matvec with LDS cache (K=512, NOUT=512) ----------
// r-slots r = ib*2+j, r<18 cached in LDS (thread-private: wlds[r*512+tid]).
template<bool FILL>
__device__ __forceinline__ void wrec_mv(const uint4* __restrict__ w,
                                        const unsigned* __restrict__ act2,
                                        uint4* __restrict__ wlds,
                                        int tid, float* out){
  const uint4* a4 = (const uint4*)act2;
  const int kh = tid & 1;
  float acc0 = 0.f, acc1 = 0.f;
  #pragma unroll 3
  for (int ib = 0; ib < 9; ++ib){
    const uint4 a = a4[2*ib + kh];
    uint4 w0, w1;
    if (FILL){
      w0 = w[(size_t)(ib*2+0)*512 + tid];
      w1 = w[(size_t)(ib*2+1)*512 + tid];
      wlds[(ib*2+0)*512 + tid] = w0;
      wlds[(ib*2+1)*512 + tid] = w1;
    } else {
      w0 = wlds[(ib*2+0)*512 + tid];
      w1 = wlds[(ib*2+1)*512 + tid];
    }
    acc0 = dot2(w0.x, a.x, acc0); acc0 = dot2(w0.y, a.y, acc0);
    acc0 = dot2(w0.z, a.z, acc0); acc0 = dot2(w0.w, a.w, acc0);
    acc1 = dot2(w1.x, a.x, acc1); acc1 = dot2(w1.y, a.y, acc1);
    acc1 = dot2(w1.z, a.z, acc1); acc1 = dot2(w1.w, a.w, acc1);
  }
  #pragma unroll 2
  for (int ib = 9; ib < 32; ++ib){
    const uint4 a  = a4[2*ib + kh];
    const uint4 w0 = w[(size_t)(ib*2+0)*512 + tid];
    const uint4 w1 = w[(size_t)(ib*2+1)*512 + tid];
    acc0 = dot2(w0.x, a.x, acc0); acc0 = dot2(w0.y, a.y, acc0);
    acc0 = dot2(w0.z, a.z, acc0); acc0 = dot2(w0.w, a.w, acc0);
    acc1 = dot2(w1.x, a.x, acc1); acc1 = dot2(w1.y, a.y, acc1);
    acc1 = dot2(w1.z, a.z, acc1); acc1 = dot2(w1.w, a.w, acc1);
  }
  acc0 += __shfl_xor(acc0, 1);
  acc1 += __shfl_xor(acc1, 1);
  out[0] = acc0; out[1] = acc1;
}

// ---------- one LTC layer step (KC = concat K, KI = I_in K) ----------
template<int KC, int KI>
__device__ __forceinline__ void ltc_step(
    float& v0, float& g0, float& v1, float& g1,
    const uint4* Ta, const uint4* Tb, const uint4* Wi, const uint4* Wr,
    const float* pvec, int cbase,
    unsigned* comb2, unsigned* thA, unsigned* thB, float* sred,
    uint4* wlds, int tid, bool fill, float& y0, float& y1)
{
  const int p = tid >> 1;
  float th_[2]; matvec2<KC, 512>(Ta, comb2, tid, th_);
  float ii[2];  matvec2<KI, 512>(Wi, comb2, tid, ii);
  const float tauh0 = ftanh(th_[0] + pvec[cbase+512+p]);
  const float tauh1 = ftanh(th_[1] + pvec[cbase+512+256+p]);
  const float iin0  = ii[0] + pvec[cbase+p];
  const float iin1  = ii[1] + pvec[cbase+256+p];
  float h0 = ftanh(v0), h1 = ftanh(v1);
  {
    const float a = __shfl_down(tauh0, 2), bq = __shfl_down(tauh1, 2);
    const float c = __shfl_down(h0, 2),    d  = __shfl_down(h1, 2);
    if (!(tid & 3)){
      thA[tid>>2] = pack2(tauh0, a); thA[128+(tid>>2)] = pack2(tauh1, bq);
      thB[tid>>2] = pack2(h0, c);    thB[128+(tid>>2)] = pack2(h1, d);
    }
  }
  __syncthreads();                       // thA (tau_h), thB (tanh v) ready
  float tt[2]; matvec2<512, 512>(Tb, thA, tid, tt);
  const float tau0 = 0.1f + 9.9f * fsig(tt[0] + pvec[cbase+1024+p]);
  const float tau1 = 0.1f + 9.9f * fsig(tt[1] + pvec[cbase+1024+256+p]);
  const float ga0 = 0.2f/tau0, va0 = 0.1f/tau0;
  const float ga1 = 0.2f/tau1, va1 = 0.1f/tau1;
  const float gl0 = pvec[cbase+1536+p], gl1 = pvec[cbase+1536+256+p];
  const float gs0 = pvec[cbase+2048+p], gs1 = pvec[cbase+2048+256+p];
  __syncthreads();                       // thA reads done
  #pragma unroll 1
  for (int u = 0; u < 6; ++u){
    unsigned* cur = (u & 1) ? thA : thB;
    unsigned* nxt = (u & 1) ? thB : thA;
    float ir[2];
    if (fill && u == 0) wrec_mv<true >(Wr, cur, wlds, tid, ir);
    else                wrec_mv<false>(Wr, cur, wlds, tid, ir);
    g0 += (fsig(iin0 + ir[0]) - g0) * ga0;
    v0 += (gs0*g0*(1.f - v0) - gl0*v0) * va0;
    v0 = fminf(5.f, fmaxf(-5.f, v0)); h0 = ftanh(v0);
    g1 += (fsig(iin1 + ir[1]) - g1) * ga1;
    v1 += (gs1*g1*(1.f - v1) - gl1*v1) * va1;
    v1 = fminf(5.f, fmaxf(-5.f, v1)); h1 = ftanh(v1);
    const float c = __shfl_down(h0, 2), d = __shfl_down(h1, 2);
    if (!(tid & 3)){ nxt[tid>>2] = pack2(h0, c); nxt[128+(tid>>2)] = pack2(h1, d); }
    __syncthreads();
  }
  // layernorm over 512 outputs (odd lanes are duplicates -> mask)
  float s1 = (tid & 1) ? 0.f : (h0 + h1);
  float s2 = (tid & 1) ? 0.f : (h0*h0 + h1*h1);
  #pragma unroll
  for (int off = 32; off >= 1; off >>= 1){
    s1 += __shfl_down(s1, off); s2 += __shfl_down(s2, off);
  }
  const int lane = tid & 63, wid = tid >> 6;
  if (lane == 0){ sred[wid] = s1; sred[8 + wid] = s2; }
  __syncthreads();
  float S1 = 0.f, S2 = 0.f;
  #pragma unroll
  for (int w2 = 0; w2 < 8; ++w2){ S1 += sred[w2]; S2 += sred[8 + w2]; }
  const float m = S1 * (1.f/512.f);
  const float varr = S2 * (1.f/512.f) - m*m;
  const float rs = rsqrtf(varr + 1e-5f);
  y0 = (h0 - m)*rs*pvec[cbase+2560+p]     + pvec[cbase+3072+p];
  y1 = (h1 - m)*rs*pvec[cbase+2560+256+p] + pvec[cbase+3072+256+p];
  __syncthreads();                       // sred/thA/thB reusable
}

// ---------- packed-weight offsets (uint4 units) ----------
#define PK_WIN0   0
#define PK_WREC0  16384
#define PK_TA0    49152
#define PK_TB0    98304
#define PK_WIN1   131072
#define PK_WREC1  163840
#define PK_TA1    196608
#define PK_TB1    262144
#define PK_WQ     294912
#define PK_WK     327680
#define PK_WV     360448
#define PK_AO     393216
#define PK_P1     425984
#define PK_P2     442368
#define PK_TOTAL  450560

// ---------- dtype detection ----------
__global__ void detect_kernel(const unsigned* __restrict__ x, int* __restrict__ flag){
  int cnt = 0;
  for (int i = threadIdx.x; i < 4096; i += 256){
    const unsigned e = (x[i] >> 7) & 0xFFu;
    cnt += (e == 0u || e == 0xFFu) ? 1 : 0;
  }
  __shared__ int sh[4];
  #pragma unroll
  for (int off = 32; off >= 1; off >>= 1) cnt += __shfl_down(cnt, off);
  if ((threadIdx.x & 63) == 0) sh[threadIdx.x >> 6] = cnt;
  __syncthreads();
  if (threadIdx.x == 0) *flag = (sh[0]+sh[1]+sh[2]+sh[3] > 4) ? 1 : 0;
}

// ---------- weight packing: u -> (tid, r) -> (o, k-octet) ----------
struct PackDesc {
  const void* src[14];
  long eoff[14];
  int kdiv8[14];
  int lg2n[14];
  int cum[15];
};
__global__ void pack_kernel(PackDesc d, const int* __restrict__ flag,
                            uint4* __restrict__ out){
  const int u = blockIdx.x * 256 + threadIdx.x;
  if (u >= d.cum[14]) return;
  int s = 0;
  #pragma unroll
  for (int i = 1; i < 14; ++i) if (u >= d.cum[i]) s = i;
  const int local = u - d.cum[s];
  const int tid = local & 511;
  const int r   = local >> 9;
  const int lgnj = d.lg2n[s] - 8;              // 1 (NOUT=512) or 0 (256)
  const int j  = r & ((1 << lgnj) - 1);
  const int ib = r >> lgnj;
  const int p  = tid >> 1, kh = tid & 1;
  const int o  = (j << 8) + p;
  const long base = (long)o * (d.kdiv8[s] * 8) + (long)(2*ib + kh) * 8;
  if (*flag){
    const float* sp = (const float*)d.src[s] + d.eoff[s];
    unsigned short h[8];
    #pragma unroll
    for (int i = 0; i < 8; ++i) h[i] = f2b(sp[base + i]);
    uint4 o4;
    o4.x = (unsigned)h[0] | ((unsigned)h[1] << 16);
    o4.y = (unsigned)h[2] | ((unsigned)h[3] << 16);
    o4.z = (unsigned)h[4] | ((unsigned)h[5] << 16);
    o4.w = (unsigned)h[6] | ((unsigned)h[7] << 16);
    out[u] = o4;
  } else {
    const unsigned short* sp = (const unsigned short*)d.src[s] + d.eoff[s];
    out[u] = *(const uint4*)(sp + base);
  }
}

struct VecDesc {
  const void* src[18];
  int n[18];
  int dst[18];
};
__global__ void vec_kernel(VecDesc d, const int* __restrict__ flag,
                           float* __restrict__ pvec){
  const int s = blockIdx.x;
  const int f = *flag;
  for (int i = threadIdx.x; i < d.n[s]; i += blockDim.x)
    pvec[d.dst[s] + i] = f ? ((const float*)d.src[s])[i]
                           : b2f(((const unsigned short*)d.src[s])[i]);
}

__global__ void zflags_kernel(int* __restrict__ aflag, int* __restrict__ cflag){
  const int i = threadIdx.x;
  if (i < 64) aflag[i] = 0; else cflag[i - 64] = 0;
}

// ---------- layer-pipelined scan ----------
#define SCAN_SMEM 151808   // 4352 header + 18*512*16 Wrec LDS cache
__global__ __launch_bounds__(512, 2)
__attribute__((amdgpu_waves_per_eu(2)))
void scan_kernel(
    const void* __restrict__ xin,
    const uint4* __restrict__ wp,
    const float* __restrict__ pvec,
    const int* __restrict__ flagp,
    unsigned* __restrict__ seqw,
    unsigned* __restrict__ ring,
    int* __restrict__ aflag,
    int* __restrict__ cflag)
{
  extern __shared__ __align__(16) char smem[];
  unsigned* comb2 = (unsigned*)smem;               // 512 uints
  unsigned* thA   = comb2 + 512;                   // 256
  unsigned* thB   = thA + 256;                     // 256
  float*    sred  = (float*)(thB + 256);           // 16 floats
  uint4*    wlds  = (uint4*)(smem + 4352);         // 18*512 uint4

  const int tid = threadIdx.x;
  const int blk = blockIdx.x;
  const int b   = blk & 63;
  const bool isB = blk >= 64;
  const int isf32 = *flagp;
  const int cbase = isB ? 3584 : 0;
  const uint4* Ta = wp + (isB ? PK_TA1  : PK_TA0);
  const uint4* Tb = wp + (isB ? PK_TB1  : PK_TB0);
  const uint4* Wi = wp + (isB ? PK_WIN1 : PK_WIN0);
  const uint4* Wr = wp + (isB ? PK_WREC1: PK_WREC0);

  float v0 = 0.f, g0 = 0.f, v1 = 0.f, g1 = 0.f;

  #pragma unroll 1
  for (int t = 0; t < 512; ++t){
    if (!isB){
      // comb2 = [x 128 | v pairs 256]
      if (tid < 128){
        const size_t idx = ((size_t)b*512 + t)*128 + tid;
        if (isf32){
          const float2 xv = ((const float2*)xin)[idx];
          comb2[tid] = pack2(xv.x, xv.y);
        } else {
          comb2[tid] = ((const unsigned*)xin)[idx];
        }
      }
      {
        const float a = __shfl_down(v0, 2), c = __shfl_down(v1, 2);
        if (!(tid & 3)){
          comb2[128 + (tid>>2)] = pack2(v0, a);
          comb2[256 + (tid>>2)] = pack2(v1, c);
        }
      }
      __syncthreads();
      float y0, y1;
      ltc_step<768, 256>(v0, g0, v1, g1, Ta, Tb, Wi, Wr, pvec, cbase,
                         comb2, thA, thB, sred, wlds, tid, t == 0, y0, y1);
      const float a = __shfl_down(y0, 2), c = __shfl_down(y1, 2);
      if (tid == 0 && t >= 8){
        while (__hip_atomic_load(&cflag[b], __ATOMIC_ACQUIRE,
                                 __HIP_MEMORY_SCOPE_AGENT) < t - 7)
          __builtin_amdgcn_s_sleep(1);
      }
      __syncthreads();
      if (!(tid & 3)){
        unsigned* dst = ring + ((size_t)b*8 + (t & 7))*256;
        __hip_atomic_store(dst + (tid>>2), pack2(y0, a),
                           __ATOMIC_RELAXED, __HIP_MEMORY_SCOPE_AGENT);
        __hip_atomic_store(dst + 128 + (tid>>2), pack2(y1, c),
                           __ATOMIC_RELAXED, __HIP_MEMORY_SCOPE_AGENT);
      }
      __syncthreads();
      if (tid == 0)
        __hip_atomic_store(&aflag[b], t + 1, __ATOMIC_RELEASE,
                           __HIP_MEMORY_SCOPE_AGENT);
    } else {
      if (tid == 0){
        while (__hip_atomic_load(&aflag[b], __ATOMIC_ACQUIRE,
                                 __HIP_MEMORY_SCOPE_AGENT) < t + 1)
          __builtin_amdgcn_s_sleep(1);
      }
      __syncthreads();
      if (tid < 256){
        const unsigned* src = ring + ((size_t)b*8 + (t & 7))*256;
        comb2[tid] = __hip_atomic_load(src + tid, __ATOMIC_RELAXED,
                                       __HIP_MEMORY_SCOPE_AGENT);
      }
      {
        const float a = __shfl_down(v0, 2), c = __shfl_down(v1, 2);
        if (!(tid & 3)){
          comb2[256 + (tid>>2)] = pack2(v0, a);
          comb2[384 + (tid>>2)] = pack2(v1, c);
        }
      }
      __syncthreads();
      float y0, y1;
      ltc_step<1024, 512>(v0, g0, v1, g1, Ta, Tb, Wi, Wr, pvec, cbase,
                          comb2, thA, thB, sred, wlds, tid, t == 0, y0, y1);
      const float a = __shfl_down(y0, 2), c = __shfl_down(y1, 2);
      if (!(tid & 3)){
        unsigned* dst = seqw + ((size_t)b*512 + t)*256;
        dst[tid>>2]       = pack2(y0, a);
        dst[128+(tid>>2)] = pack2(y1, c);
      }
      __syncthreads();
      if (tid == 0)
        __hip_atomic_store(&cflag[b], t + 1, __ATOMIC_RELEASE,
                           __HIP_MEMORY_SCOPE_AGENT);
    }
  }
}

// ---------- Q projection for t = T-1 ----------
__global__ __launch_bounds__(512) void q_kernel(
    const unsigned* __restrict__ seqw, const uint4* __restrict__ wp,
    const float* __restrict__ pvec, float* __restrict__ qws)
{
  __shared__ __align__(16) unsigned act2[256];
  const int tid = threadIdx.x, b = blockIdx.x, p = tid >> 1;
  if (tid < 256) act2[tid] = seqw[((size_t)(b*512 + 511))*256 + tid];
  __syncthreads();
  float q[2]; matvec2<512, 512>(wp + PK_WQ, act2, tid, q);
  if (!(tid & 1)){
    qws[b*512 + p]       = q[0] + pvec[7168 + p];
    qws[b*512 + 256 + p] = q[1] + pvec[7168 + 256 + p];
  }
}

// ---------- scores: one block per (b,t) ----------
__global__ __launch_bounds__(512) void score_kernel(
    const unsigned* __restrict__ seqw, const uint4* __restrict__ wp,
    const float* __restrict__ pvec, const float* __restrict__ qws,
    float* __restrict__ sws)
{
  __shared__ __align__(16) unsigned act2[256];
  __shared__ float hrA[8], hrB[8];
  const int tid = threadIdx.x, p = tid >> 1;
  const int r = blockIdx.x, b = r >> 9, t = r & 511;
  if (tid < 256) act2[tid] = seqw[(size_t)r*256 + tid];
  __syncthreads();
  float kk[2]; matvec2<512, 512>(wp + PK_WK, act2, tid, kk);
  float pa = (tid & 1) ? 0.f : (kk[0] + pvec[7680 + p])       * qws[b*512 + p];
  float pb = (tid & 1) ? 0.f : (kk[1] + pvec[7680 + 256 + p]) * qws[b*512 + 256 + p];
  #pragma unroll
  for (int off = 32; off >= 1; off >>= 1){
    pa += __shfl_down(pa, off); pb += __shfl_down(pb, off);
  }
  const int lane = tid & 63, wid = tid >> 6;
  if (lane == 0){ hrA[wid] = pa; hrB[wid] = pb; }
  __syncthreads();
  if (tid < 4){
    float s;
    if      (tid == 0) s = hrA[0]+hrA[1]+hrA[2]+hrA[3];
    else if (tid == 1) s = hrA[4]+hrA[5]+hrA[6]+hrA[7];
    else if (tid == 2) s = hrB[0]+hrB[1]+hrB[2]+hrB[3];
    else               s = hrB[4]+hrB[5]+hrB[6]+hrB[7];
    sws[((size_t)(b*4 + tid))*512 + t] = s * 0.08838834764831845f;
  }
}

// ---------- softmax over t per (b,h); zero-init oacc ----------
__global__ __launch_bounds__(512) void softmax_kernel(
    const float* __restrict__ sws, float* __restrict__ pws,
    float* __restrict__ oacc)
{
  __shared__ float rw[16];
  const int tid = threadIdx.x, bh = blockIdx.x;
  const float s = sws[(size_t)bh*512 + tid];
  float mx = s;
  #pragma unroll
  for (int off = 32; off >= 1; off >>= 1) mx = fmaxf(mx, __shfl_down(mx, off));
  const int lane = tid & 63, wid = tid >> 6;
  if (lane == 0) rw[wid] = mx;
  __syncthreads();
  mx = rw[0];
  #pragma unroll
  for (int w2 = 1; w2 < 8; ++w2) mx = fmaxf(mx, rw[w2]);
  const float e = __expf(s - mx);
  float sm = e;
  #pragma unroll
  for (int off = 32; off >= 1; off >>= 1) sm += __shfl_down(sm, off);
  if (lane == 0) rw[8 + wid] = sm;
  __syncthreads();
  sm = 0.f;
  #pragma unroll
  for (int w2 = 0; w2 < 8; ++w2) sm += rw[8 + w2];
  pws[(size_t)bh*512 + tid] = e / sm;
  if (tid < 128) oacc[(bh >> 2)*512 + (bh & 3)*128 + tid] = 0.f;
}

// ---------- V-accumulate: block = (b, 64-t chunk) ----------
__global__ __launch_bounds__(512) void vacc_kernel(
    const unsigned* __restrict__ seqw, const uint4* __restrict__ wp,
    const float* __restrict__ pvec, const float* __restrict__ pws,
    float* __restrict__ oacc)
{
  __shared__ __align__(16) unsigned act2[256];
  const int tid = threadIdx.x, p = tid >> 1;
  const int blk = blockIdx.x, b = blk >> 3, ch = blk & 7;
  float a0 = 0.f, a1 = 0.f;
  #pragma unroll 1
  for (int t = ch*64; t < ch*64 + 64; ++t){
    if (tid < 256) act2[tid] = seqw[((size_t)b*512 + t)*256 + tid];
    __syncthreads();
    float vv[2]; matvec2<512, 512>(wp + PK_WV, act2, tid, vv);
    if (!(tid & 1)){
      a0 += (vv[0] + pvec[8192 + p])       * pws[(size_t)(b*4 + (p>>7))*512 + t];
      a1 += (vv[1] + pvec[8192 + 256 + p]) * pws[(size_t)(b*4 + 2 + (p>>7))*512 + t];
    }
    __syncthreads();
  }
  if (!(tid & 1)){
    atomicAdd(&oacc[b*512 + p], a0);
    atomicAdd(&oacc[b*512 + 256 + p], a1);
  }
}

// ---------- tail ----------
__global__ __launch_bounds__(512) void final_kernel(
    const float* __restrict__ oacc, const uint4* __restrict__ wp,
    const float* __restrict__ pvec, const int* __restrict__ flagp,
    void* __restrict__ out)
{
  __shared__ __align__(16) unsigned a2[256];
  const int tid = threadIdx.x, b = blockIdx.x, p = tid >> 1;
  const int isf32 = *flagp;
  {
    const float x0 = oacc[b*512 + p], x1 = oacc[b*512 + 256 + p];
    const float xa = __shfl_down(x0, 2), xb = __shfl_down(x1, 2);
    if (!(tid & 3)){ a2[tid>>2] = pack2(x0, xa); a2[128+(tid>>2)] = pack2(x1, xb); }
  }
  __syncthreads();
  float t1[2]; matvec2<512, 512>(wp + PK_AO, a2, tid, t1);
  t1[0] += pvec[8704 + p]; t1[1] += pvec[8704 + 256 + p];
  __syncthreads();
  {
    const float ta = __shfl_down(t1[0], 2), tb = __shfl_down(t1[1], 2);
    if (!(tid & 3)){ a2[tid>>2] = pack2(t1[0], ta); a2[128+(tid>>2)] = pack2(t1[1], tb); }
  }
  __syncthreads();
  float t2[1]; matvec2<512, 256>(wp + PK_P1, a2, tid, t2);
  t2[0] = fmaxf(0.f, t2[0] + pvec[9216 + p]);
  __syncthreads();
  {
    const float ta = __shfl_down(t2[0], 2);
    if (!(tid & 3)) a2[tid>>2] = pack2(t2[0], ta);
  }
  __syncthreads();
  float r[1]; matvec2<256, 256>(wp + PK_P2, a2, tid, r);
  if (!(tid & 1)){
    const float rr = r[0] + pvec[9472 + p];
    if (isf32) ((float*)out)[b*256 + p] = rr;
    else       ((unsigned short*)out)[b*256 + p] = f2b(rr);
  }
}

// ---------- fallback if ws too small ----------
__global__ void zero_kernel(unsigned* __restrict__ p, int n){
  const int i = blockIdx.x * 1024 + threadIdx.x;
  if (i < n) p[i] = 0;
}

// ============================================================
extern "C" void kernel_launch(void* const* d_in, const int* in_sizes, int n_in,
                              void* d_out, int out_size, void* d_ws, size_t ws_size,
                              hipStream_t stream)
{
  (void)in_sizes; (void)n_in; (void)out_size;

  if (ws_size < ((size_t)44 << 20)){
    zero_kernel<<<8, 1024, 0, stream>>>((unsigned*)d_out, 8192);
    return;
  }

  hipFuncSetAttribute((const void*)scan_kernel,
                      hipFuncAttributeMaxDynamicSharedMemorySize, SCAN_SMEM);

  char* ws = (char*)d_ws;
  int*      flag   = (int*)ws;
  int*      aflag  = (int*)(ws + 256);
  int*      cflag  = (int*)(ws + 512);
  float*    pvec   = (float*)(ws + 4096);
  uint4*    packed = (uint4*)(ws + 65536);
  unsigned* seq    = (unsigned*)(ws + ((size_t)8 << 20));     // 32 MB
  unsigned* ring   = (unsigned*)(ws + ((size_t)40 << 20));    // 512 KB
  float*    sws    = (float*)(ws + ((size_t)41 << 20));       // 512 KB
  float*    pws    = (float*)(ws + ((size_t)41 << 20) + 524288);
  float*    qws    = (float*)(ws + ((size_t)42 << 20));
  float*    oacc   = (float*)(ws + ((size_t)42 << 20) + 262144);

  detect_kernel<<<1, 256, 0, stream>>>((const unsigned*)d_in[0], flag);
  zflags_kernel<<<1, 128, 0, stream>>>(aflag, cflag);

  PackDesc pd;
  const void* msrc[14] = {
    d_in[1], d_in[3], d_in[4], d_in[6],
    d_in[12], d_in[14], d_in[15], d_in[17],
    d_in[23], d_in[23], d_in[23],
    d_in[25], d_in[27], d_in[29]
  };
  const long eoff[14] = {0,0,0,0, 0,0,0,0, 0, 262144, 524288, 0, 0, 0};
  const int kk8[14]  = {32,64,96,64, 64,64,128,64, 64,64,64, 64, 64, 32};
  const int ln2[14]  = {9,9,9,9, 9,9,9,9, 9,9,9, 9, 8, 8};
  const int cum[15]  = {0,16384,49152,98304,131072,163840,196608,262144,
                        294912,327680,360448,393216,425984,442368,450560};
  for (int i = 0; i < 14; ++i){
    pd.src[i]=msrc[i]; pd.eoff[i]=eoff[i]; pd.kdiv8[i]=kk8[i]; pd.lg2n[i]=ln2[i];
  }
  for (int i = 0; i < 15; ++i) pd.cum[i] = cum[i];
  pack_kernel<<<(PK_TOTAL + 255)/256, 256, 0, stream>>>(pd, flag, packed);

  VecDesc vd;
  const void* vsrc[18] = {
    d_in[2], d_in[5], d_in[7], d_in[8], d_in[9], d_in[10], d_in[11],
    d_in[13], d_in[16], d_in[18], d_in[19], d_in[20], d_in[21], d_in[22],
    d_in[24], d_in[26], d_in[28], d_in[30]
  };
  const int vn[18]  = {512,512,512,512,512,512,512, 512,512,512,512,512,512,512,
                       1536,512,256,256};
  const int vds[18] = {0,512,1024,1536,2048,2560,3072,
                       3584,4096,4608,5120,5632,6144,6656,
                       7168,8704,9216,9472};
  for (int i = 0; i < 18; ++i){ vd.src[i]=vsrc[i]; vd.n[i]=vn[i]; vd.dst[i]=vds[i]; }
  vec_kernel<<<18, 512, 0, stream>>>(vd, flag, pvec);

  scan_kernel<<<128, 512, SCAN_SMEM, stream>>>(d_in[0], packed, pvec, flag,
                                               seq, ring, aflag, cflag);
  q_kernel<<<64, 512, 0, stream>>>(seq, packed, pvec, qws);
  score_kernel<<<64*512, 512, 0, stream>>>(seq, packed, pvec, qws, sws);
  softmax_kernel<<<256, 512, 0, stream>>>(sws, pws, oacc);
  vacc_kernel<<<512, 512, 0, stream>>>(seq, packed, pvec, pws, oacc);
  final_kernel<<<64, 512, 0, stream>>>(oacc, packed, pvec, flag, d_out);
}

// Round 9
// 25194.199 us; speedup vs baseline: 2.8846x; 1.3743x over previous
//
#include <hip/hip_runtime.h>
#include <stdint.h>

// ============================================================
// AdaptiveLNN on MI355X, round 8: layer-pipeline + full occupancy.
// r8 insight: 512-thread blocks (2 waves/SIMD) are latency-bound at
// 66 GB/s/CU realized; r3's 1024-thread blocks reached 235 GB/s/CU.
// This round: 128 blocks x 1024 threads (16 waves/CU, 1 block/CU via
// 151KB LDS). Blocks [0,64) = layer0, [64,128) = layer1 one step back,
// h0 through an 8-deep ring with agent-scope atomics. 9/32 Wrec slots
// LDS-resident (147KB, filled at t=0). ~4.4 MB/step/CU streamed.
// ============================================================

__device__ __forceinline__ float b2f(unsigned short s){
  union { unsigned i; float f; } c; c.i = ((unsigned)s) << 16; return c.f;
}
__device__ __forceinline__ unsigned short f2b(float f){
  union { unsigned i; float f; } c; c.f = f;
  unsigned r = c.i + 0x7fffu + ((c.i >> 16) & 1u);
  return (unsigned short)(r >> 16);
}
__device__ __forceinline__ unsigned pack2(float a, float b){
  return (unsigned)f2b(a) | ((unsigned)f2b(b) << 16);
}
__device__ __forceinline__ float fsig(float x){ return 1.f/(1.f+__expf(-x)); }
__device__ __forceinline__ float ftanh(float x){ return 1.f - 2.f/(__expf(2.f*x)+1.f); }

#if __has_builtin(__builtin_amdgcn_fdot2_f32_bf16)
typedef __bf16 bf16x2_t __attribute__((ext_vector_type(2)));
__device__ __forceinline__ float dot2(unsigned w, unsigned a, float acc){
  union U { unsigned u; bf16x2_t v; };
  U cw; cw.u = w; U ca; ca.u = a;
  return __builtin_amdgcn_fdot2_f32_bf16(cw.v, ca.v, acc, false);
}
#else
__device__ __forceinline__ float dot2(unsigned w, unsigned a, float acc){
  asm("v_dot2_f32_bf16 %0, %1, %2, %0" : "+v"(acc) : "v"(w), "v"(a));
  return acc;
}
#endif

// ---------- 1024-thread full-dot matvec (scan): o=tid>>1, kh=tid&1 ----------
// Weight layout A: w[(size_t)i*1024 + tid] = 8 bf16 of row o, k-octet 2i+kh.
template<int K, int NOUT>
__device__ __forceinline__ float matvecF(const uint4* __restrict__ w,
                                         const unsigned* __restrict__ act2,
                                         int tid){
  constexpr int NI = K / 16;
  float acc0 = 0.f, acc1 = 0.f;
  const uint4* a4 = (const uint4*)act2;
  const int kh = tid & 1;
  #pragma unroll 8
  for (int i = 0; i < NI; ++i){
    const uint4 wv = w[(size_t)i*(2*NOUT) + tid];
    const uint4 a  = a4[2*i + kh];
    acc0 = dot2(wv.x, a.x, acc0);
    acc0 = dot2(wv.y, a.y, acc0);
    acc1 = dot2(wv.z, a.z, acc1);
    acc1 = dot2(wv.w, a.w, acc1);
  }
  float acc = acc0 + acc1;
  acc += __shfl_xor(acc, 1);
  return acc;
}

// ---------- Wrec matvec, 9/32 slots LDS-cached (K=512, NOUT=512) ----------
template<bool FILL>
__device__ __forceinline__ float wrecF(const uint4* __restrict__ w,
                                       const unsigned* __restrict__ act2,
                                       uint4* __restrict__ wlds, int tid){
  float acc0 = 0.f, acc1 = 0.f;
  const uint4* a4 = (const uint4*)act2;
  const int kh = tid & 1;
  #pragma unroll 3
  for (int i = 0; i < 9; ++i){
    uint4 wv;
    if (FILL){ wv = w[(size_t)i*1024 + tid]; wlds[i*1024 + tid] = wv; }
    else     { wv = wlds[i*1024 + tid]; }
    const uint4 a = a4[2*i + kh];
    acc0 = dot2(wv.x, a.x, acc0);
    acc0 = dot2(wv.y, a.y, acc0);
    acc1 = dot2(wv.z, a.z, acc1);
    acc1 = dot2(wv.w, a.w, acc1);
  }
  #pragma unroll 4
  for (int i = 9; i < 32; ++i){
    const uint4 wv = w[(size_t)i*1024 + tid];
    const uint4 a  = a4[2*i + kh];
    acc0 = dot2(wv.x, a.x, acc0);
    acc0 = dot2(wv.y, a.y, acc0);
    acc1 = dot2(wv.z, a.z, acc1);
    acc1 = dot2(wv.w, a.w, acc1);
  }
  float acc = acc0 + acc1;
  acc += __shfl_xor(acc, 1);
  return acc;
}

// ---------- one LTC layer, one timestep (1024 threads, cached Wrec) ----------
template<int KC, int KI>
__device__ __forceinline__ float layer_stepP(
    float& v, float& g,
    const uint4* Wi, const uint4* Wr, const uint4* Ta, const uint4* Tb,
    float wb, float tab, float tbb, float gl, float gs, float lw, float lb,
    unsigned* comb2, unsigned* thA, unsigned* thB, float* sred,
    uint4* wlds, int tid, bool fill)
{
  float tauh = matvecF<KC, 512>(Ta, comb2, tid);
  float iin  = matvecF<KI, 512>(Wi, comb2, tid) + wb;
  tauh = ftanh(tauh + tab);
  float hv = ftanh(v);
  {
    const float tp = __shfl_down(tauh, 2);
    const float hp = __shfl_down(hv, 2);
    if (!(tid & 3)){ thA[tid >> 2] = pack2(tauh, tp); thB[tid >> 2] = pack2(hv, hp); }
  }
  __syncthreads();                        // thA (tau_h), thB (tanh v) ready
  float tau = matvecF<512, 512>(Tb, thA, tid);
  tau = 0.1f + 9.9f * fsig(tau + tbb);
  const float ga = 0.2f / tau;
  const float va = 0.1f / tau;
  __syncthreads();                        // thA reads done; unfolds may overwrite
  float h = hv;
  #pragma unroll 1
  for (int u = 0; u < 6; ++u){
    unsigned* cur = (u & 1) ? thA : thB;
    unsigned* nxt = (u & 1) ? thB : thA;
    const float irec = (fill && u == 0)
        ? wrecF<true >(Wr, cur, wlds, tid)
        : wrecF<false>(Wr, cur, wlds, tid);
    g += (fsig(iin + irec) - g) * ga;
    v += (gs * g * (1.f - v) - gl * v) * va;
    v = fminf(5.f, fmaxf(-5.f, v));
    h = ftanh(v);
    const float hp = __shfl_down(h, 2);
    if (!(tid & 3)) nxt[tid >> 2] = pack2(h, hp);
    __syncthreads();                      // one barrier per unfold
  }
  // layernorm over 512 outputs (mask duplicate odd lanes)
  const float hm = (tid & 1) ? 0.f : h;
  float s1 = hm, s2 = hm * hm;
  #pragma unroll
  for (int off = 32; off >= 1; off >>= 1){
    s1 += __shfl_down(s1, off);
    s2 += __shfl_down(s2, off);
  }
  const int lane = tid & 63, wid = tid >> 6;
  if (lane == 0){ sred[wid] = s1; sred[16 + wid] = s2; }
  __syncthreads();
  float S1 = 0.f, S2 = 0.f;
  #pragma unroll
  for (int w2 = 0; w2 < 16; ++w2){ S1 += sred[w2]; S2 += sred[16 + w2]; }
  const float m    = S1 * (1.f/512.f);
  const float varr = S2 * (1.f/512.f) - m * m;
  const float y = (h - m) * rsqrtf(varr + 1e-5f) * lw + lb;
  __syncthreads();                        // sred/thA/thB reusable
  return y;
}

// ---------- 512-thread matvec (tail kernels): p=tid>>1, kh=tid&1 ----------
// Weight layout B: w[(ib*NJ+j)*512 + tid] = row j*256+p, k-octet 2ib+kh.
template<int K, int NOUT>
__device__ __forceinline__ void matvec2(const uint4* __restrict__ w,
                                        const unsigned* __restrict__ act2,
                                        int tid, float* out){
  constexpr int NJ = NOUT/256, NIB = K/16;
  const uint4* a4 = (const uint4*)act2;
  const int kh = tid & 1;
  float acc[NJ];
  #pragma unroll
  for (int j = 0; j < NJ; ++j) acc[j] = 0.f;
  #pragma unroll 2
  for (int ib = 0; ib < NIB; ++ib){
    const uint4 a = a4[2*ib + kh];
    #pragma unroll
    for (int j = 0; j < NJ; ++j){
      const uint4 wv = w[(size_t)(ib*NJ + j)*512 + tid];
      acc[j] = dot2(wv.x, a.x, acc[j]);
      acc[j] = dot2(wv.y, a.y, acc[j]);
      acc[j] = dot2(wv.z, a.z, acc[j]);
      acc[j] = dot2(wv.w, a.w, acc[j]);
    }
  }
  #pragma unroll
  for (int j = 0; j < NJ; ++j){
    float s = acc[j];
    s += __shfl_xor(s, 1);
    out[j] = s;
  }
}

// ---------- packed-weight offsets (uint4 units) ----------
#define PK_WIN0   0
#define PK_WREC0  16384
#define PK_TA0    49152
#define PK_TB0    98304
#define PK_WIN1   131072
#define PK_WREC1  163840
#define PK_TA1    196608
#define PK_TB1    262144
#define PK_WQ     294912
#define PK_WK     327680
#define PK_WV     360448
#define PK_AO     393216
#define PK_P1     425984
#define PK_P2     442368
#define PK_TOTAL  450560

// ---------- dtype detection ----------
__global__ void detect_kernel(const unsigned* __restrict__ x, int* __restrict__ flag){
  int cnt = 0;
  for (int i = threadIdx.x; i < 4096; i += 256){
    const unsigned e = (x[i] >> 7) & 0xFFu;
    cnt += (e == 0u || e == 0xFFu) ? 1 : 0;
  }
  __shared__ int sh[4];
  #pragma unroll
  for (int off = 32; off >= 1; off >>= 1) cnt += __shfl_down(cnt, off);
  if ((threadIdx.x & 63) == 0) sh[threadIdx.x >> 6] = cnt;
  __syncthreads();
  if (threadIdx.x == 0) *flag = (sh[0]+sh[1]+sh[2]+sh[3] > 4) ? 1 : 0;
}

// ---------- weight packing (dual dtype, dual layout) ----------
struct PackDesc {
  const void* src[14];
  long eoff[14];
  int kdiv8[14];
  int lg2n[14];
  int mode[14];      // 0 = 1024-thread layout (scan), 1 = 512-thread (tail)
  int cum[15];
};
__global__ void pack_kernel(PackDesc d, const int* __restrict__ flag,
                            uint4* __restrict__ out){
  const int u = blockIdx.x * 256 + threadIdx.x;
  if (u >= d.cum[14]) return;
  int s = 0;
  #pragma unroll
  for (int i = 1; i < 14; ++i) if (u >= d.cum[i]) s = i;
  const int local = u - d.cum[s];
  long base;
  if (d.mode[s] == 0){
    const int ln      = d.lg2n[s];                 // 9
    const int pairIdx = local >> (ln + 1);
    const int rem     = local & ((2 << ln) - 1);
    const int o       = rem >> 1;
    const int kh      = rem & 1;
    const int kb      = pairIdx * 2 + kh;
    base = (long)o * (d.kdiv8[s] * 8) + (long)kb * 8;
  } else {
    const int tid  = local & 511;
    const int r    = local >> 9;
    const int lgnj = d.lg2n[s] - 8;
    const int j    = r & ((1 << lgnj) - 1);
    const int ib   = r >> lgnj;
    const int p    = tid >> 1, kh = tid & 1;
    const int o    = (j << 8) + p;
    base = (long)o * (d.kdiv8[s] * 8) + (long)(2*ib + kh) * 8;
  }
  if (*flag){
    const float* sp = (const float*)d.src[s] + d.eoff[s];
    unsigned short h[8];
    #pragma unroll
    for (int i = 0; i < 8; ++i) h[i] = f2b(sp[base + i]);
    uint4 o4;
    o4.x = (unsigned)h[0] | ((unsigned)h[1] << 16);
    o4.y = (unsigned)h[2] | ((unsigned)h[3] << 16);
    o4.z = (unsigned)h[4] | ((unsigned)h[5] << 16);
    o4.w = (unsigned)h[6] | ((unsigned)h[7] << 16);
    out[u] = o4;
  } else {
    const unsigned short* sp = (const unsigned short*)d.src[s] + d.eoff[s];
    out[u] = *(const uint4*)(sp + base);
  }
}

struct VecDesc {
  const void* src[18];
  int n[18];
  int dst[18];
};
__global__ void vec_kernel(VecDesc d, const int* __restrict__ flag,
                           float* __restrict__ pvec){
  const int s = blockIdx.x;
  const int f = *flag;
  for (int i = threadIdx.x; i < d.n[s]; i += blockDim.x)
    pvec[d.dst[s] + i] = f ? ((const float*)d.src[s])[i]
                           : b2f(((const unsigned short*)d.src[s])[i]);
}

__global__ void zflags_kernel(int* __restrict__ aflag, int* __restrict__ cflag){
  const int i = threadIdx.x;
  if (i < 64) aflag[i] = 0; else cflag[i - 64] = 0;
}

// ---------- layer-pipelined scan: 128 blocks x 1024 threads ----------
#define SCAN_SMEM 151680   // 4224 header + 9*1024*16 Wrec LDS cache
__global__ __launch_bounds__(1024) void scan_kernel(
    const void* __restrict__ xin,
    const uint4* __restrict__ wp,
    const float* __restrict__ pvec,
    const int* __restrict__ flagp,
    unsigned* __restrict__ seqw,
    unsigned* __restrict__ ring,
    int* __restrict__ aflag,
    int* __restrict__ cflag)
{
  extern __shared__ __align__(16) char smem[];
  unsigned* comb2 = (unsigned*)smem;               // 512 uints
  unsigned* thA   = comb2 + 512;                   // 256
  unsigned* thB   = thA + 256;                     // 256
  float*    sred  = (float*)(thB + 256);           // 32 floats
  uint4*    wlds  = (uint4*)(smem + 4224);         // 9*1024 uint4

  const int tid = threadIdx.x;
  const int o   = tid >> 1;
  const int blk = blockIdx.x;
  const int b   = blk & 63;
  const bool isB = blk >= 64;
  const int isf32 = *flagp;
  const int cb  = isB ? 3584 : 0;

  const uint4* Ta = wp + (isB ? PK_TA1  : PK_TA0);
  const uint4* Tb = wp + (isB ? PK_TB1  : PK_TB0);
  const uint4* Wi = wp + (isB ? PK_WIN1 : PK_WIN0);
  const uint4* Wr = wp + (isB ? PK_WREC1: PK_WREC0);

  const float wb  = pvec[cb+o],      tab = pvec[cb+512+o], tbb = pvec[cb+1024+o];
  const float gl  = pvec[cb+1536+o], gs  = pvec[cb+2048+o];
  const float lw  = pvec[cb+2560+o], lb  = pvec[cb+3072+o];

  float v = 0.f, g = 0.f;

  #pragma unroll 1
  for (int t = 0; t < 512; ++t){
    if (!isB){
      // comb2 = [x 128 | v pairs 256]
      if (tid < 128){
        const size_t idx = ((size_t)b*512 + t)*128 + tid;
        if (isf32){
          const float2 xv = ((const float2*)xin)[idx];
          comb2[tid] = pack2(xv.x, xv.y);
        } else {
          comb2[tid] = ((const unsigned*)xin)[idx];
        }
      }
      {
        const float vp = __shfl_down(v, 2);
        if (!(tid & 3)) comb2[128 + (tid >> 2)] = pack2(v, vp);
      }
      __syncthreads();
      const float y = layer_stepP<768, 256>(v, g, Wi, Wr, Ta, Tb,
                                            wb, tab, tbb, gl, gs, lw, lb,
                                            comb2, thA, thB, sred, wlds,
                                            tid, t == 0);
      if (tid == 0 && t >= 8){
        while (__hip_atomic_load(&cflag[b], __ATOMIC_ACQUIRE,
                                 __HIP_MEMORY_SCOPE_AGENT) < t - 7)
          __builtin_amdgcn_s_sleep(1);
      }
      __syncthreads();
      {
        const float yp = __shfl_down(y, 2);
        if (!(tid & 3)){
          unsigned* dst = ring + ((size_t)b*8 + (t & 7))*256;
          __hip_atomic_store(dst + (tid>>2), pack2(y, yp),
                             __ATOMIC_RELAXED, __HIP_MEMORY_SCOPE_AGENT);
        }
      }
      __syncthreads();
      if (tid == 0)
        __hip_atomic_store(&aflag[b], t + 1, __ATOMIC_RELEASE,
                           __HIP_MEMORY_SCOPE_AGENT);
    } else {
      if (tid == 0){
        while (__hip_atomic_load(&aflag[b], __ATOMIC_ACQUIRE,
                                 __HIP_MEMORY_SCOPE_AGENT) < t + 1)
          __builtin_amdgcn_s_sleep(1);
      }
      __syncthreads();
      if (tid < 256){
        const unsigned* src = ring + ((size_t)b*8 + (t & 7))*256;
        comb2[tid] = __hip_atomic_load(src + tid, __ATOMIC_RELAXED,
                                       __HIP_MEMORY_SCOPE_AGENT);
      }
      {
        const float vp = __shfl_down(v, 2);
        if (!(tid & 3)) comb2[256 + (tid >> 2)] = pack2(v, vp);
      }
      __syncthreads();
      if (tid == 0)                       // ring slot consumed -> free it now
        __hip_atomic_store(&cflag[b], t + 1, __ATOMIC_RELEASE,
                           __HIP_MEMORY_SCOPE_AGENT);
      const float y = layer_stepP<1024, 512>(v, g, Wi, Wr, Ta, Tb,
                                             wb, tab, tbb, gl, gs, lw, lb,
                                             comb2, thA, thB, sred, wlds,
                                             tid, t == 0);
      {
        const float yp = __shfl_down(y, 2);
        if (!(tid & 3))
          seqw[((size_t)b*512 + t)*256 + (tid >> 2)] = pack2(y, yp);
      }
    }
  }
}

// ---------- Q projection for t = T-1 ----------
__global__ __launch_bounds__(512) void q_kernel(
    const unsigned* __restrict__ seqw, const uint4* __restrict__ wp,
    const float* __restrict__ pvec, float* __restrict__ qws)
{
  __shared__ __align__(16) unsigned act2[256];
  const int tid = threadIdx.x, b = blockIdx.x, p = tid >> 1;
  if (tid < 256) act2[tid] = seqw[((size_t)(b*512 + 511))*256 + tid];
  __syncthreads();
  float q[2]; matvec2<512, 512>(wp + PK_WQ, act2, tid, q);
  if (!(tid & 1)){
    qws[b*512 + p]       = q[0] + pvec[7168 + p];
    qws[b*512 + 256 + p] = q[1] + pvec[7168 + 256 + p];
  }
}

// ---------- scores: one block per (b,t) ----------
__global__ __launch_bounds__(512) void score_kernel(
    const unsigned* __restrict__ seqw, const uint4* __restrict__ wp,
    const float* __restrict__ pvec, const float* __restrict__ qws,
    float* __restrict__ sws)
{
  __shared__ __align__(16) unsigned act2[256];
  __shared__ float hrA[8], hrB[8];
  const int tid = threadIdx.x, p = tid >> 1;
  const int r = blockIdx.x, b = r >> 9, t = r & 511;
  if (tid < 256) act2[tid] = seqw[(size_t)r*256 + tid];
  __syncthreads();
  float kk[2]; matvec2<512, 512>(wp + PK_WK, act2, tid, kk);
  float pa = (tid & 1) ? 0.f : (kk[0] + pvec[7680 + p])       * qws[b*512 + p];
  float pb = (tid & 1) ? 0.f : (kk[1] + pvec[7680 + 256 + p]) * qws[b*512 + 256 + p];
  #pragma unroll
  for (int off = 32; off >= 1; off >>= 1){
    pa += __shfl_down(pa, off); pb += __shfl_down(pb, off);
  }
  const int lane = tid & 63, wid = tid >> 6;
  if (lane == 0){ hrA[wid] = pa; hrB[wid] = pb; }
  __syncthreads();
  if (tid < 4){
    float s;
    if      (tid == 0) s = hrA[0]+hrA[1]+hrA[2]+hrA[3];
    else if (tid == 1) s = hrA[4]+hrA[5]+hrA[6]+hrA[7];
    else if (tid == 2) s = hrB[0]+hrB[1]+hrB[2]+hrB[3];
    else               s = hrB[4]+hrB[5]+hrB[6]+hrB[7];
    sws[((size_t)(b*4 + tid))*512 + t] = s * 0.08838834764831845f;
  }
}

// ---------- softmax over t per (b,h); zero-init oacc ----------
__global__ __launch_bounds__(512) void softmax_kernel(
    const float* __restrict__ sws, float* __restrict__ pws,
    float* __restrict__ oacc)
{
  __shared__ float rw[16];
  const int tid = threadIdx.x, bh = blockIdx.x;
  const float s = sws[(size_t)bh*512 + tid];
  float mx = s;
  #pragma unroll
  for (int off = 32; off >= 1; off >>= 1) mx = fmaxf(mx, __shfl_down(mx, off));
  const int lane = tid & 63, wid = tid >> 6;
  if (lane == 0) rw[wid] = mx;
  __syncthreads();
  mx = rw[0];
  #pragma unroll
  for (int w2 = 1; w2 < 8; ++w2) mx = fmaxf(mx, rw[w2]);
  const float e = __expf(s - mx);
  float sm = e;
  #pragma unroll
  for (int off = 32; off >= 1; off >>= 1) sm += __shfl_down(sm, off);
  if (lane == 0) rw[8 + wid] = sm;
  __syncthreads();
  sm = 0.f;
  #pragma unroll
  for (int w2 = 0; w2 < 8; ++w2) sm += rw[8 + w2];
  pws[(size_t)bh*512 + tid] = e / sm;
  if (tid < 128) oacc[(bh >> 2)*512 + (bh & 3)*128 + tid] = 0.f;
}

// ---------- V-accumulate: block = (b, 64-t chunk) ----------
__global__ __launch_bounds__(512) void vacc_kernel(
    const unsigned* __restrict__ seqw, const uint4* __restrict__ wp,
    const float* __restrict__ pvec, const float* __restrict__ pws,
    float* __restrict__ oacc)
{
  __shared__ __align__(16) unsigned act2[256];
  const int tid = threadIdx.x, p = tid >> 1;
  const int blk = blockIdx.x, b = blk >> 3, ch = blk & 7;
  float a0 = 0.f, a1 = 0.f;
  #pragma unroll 1
  for (int t = ch*64; t < ch*64 + 64; ++t){
    if (tid < 256) act2[tid] = seqw[((size_t)b*512 + t)*256 + tid];
    __syncthreads();
    float vv[2]; matvec2<512, 512>(wp + PK_WV, act2, tid, vv);
    if (!(tid & 1)){
      a0 += (vv[0] + pvec[8192 + p])       * pws[(size_t)(b*4 + (p>>7))*512 + t];
      a1 += (vv[1] + pvec[8192 + 256 + p]) * pws[(size_t)(b*4 + 2 + (p>>7))*512 + t];
    }
    __syncthreads();
  }
  if (!(tid & 1)){
    atomicAdd(&oacc[b*512 + p], a0);
    atomicAdd(&oacc[b*512 + 256 + p], a1);
  }
}

// ---------- tail ----------
__global__ __launch_bounds__(512) void final_kernel(
    const float* __restrict__ oacc, const uint4* __restrict__ wp,
    const float* __restrict__ pvec, const int* __restrict__ flagp,
    void* __restrict__ out)
{
  __shared__ __align__(16) unsigned a2[256];
  const int tid = threadIdx.x, b = blockIdx.x, p = tid >> 1;
  const int isf32 = *flagp;
  {
    const float x0 = oacc[b*512 + p], x1 = oacc[b*512 + 256 + p];
    const float xa = __shfl_down(x0, 2), xb = __shfl_down(x1, 2);
    if (!(tid & 3)){ a2[tid>>2] = pack2(x0, xa); a2[128+(tid>>2)] = pack2(x1, xb); }
  }
  __syncthreads();
  float t1[2]; matvec2<512, 512>(wp + PK_AO, a2, tid, t1);
  t1[0] += pvec[8704 + p]; t1[1] += pvec[8704 + 256 + p];
  __syncthreads();
  {
    const float ta = __shfl_down(t1[0], 2), tb = __shfl_down(t1[1], 2);
    if (!(tid & 3)){ a2[tid>>2] = pack2(t1[0], ta); a2[128+(tid>>2)] = pack2(t1[1], tb); }
  }
  __syncthreads();
  float t2[1]; matvec2<512, 256>(wp + PK_P1, a2, tid, t2);
  t2[0] = fmaxf(0.f, t2[0] + pvec[9216 + p]);
  __syncthreads();
  {
    const float ta = __shfl_down(t2[0], 2);
    if (!(tid & 3)) a2[tid>>2] = pack2(t2[0], ta);
  }
  __syncthreads();
  float r[1]; matvec2<256, 256>(wp + PK_P2, a2, tid, r);
  if (!(tid & 1)){
    const float rr = r[0] + pvec[9472 + p];
    if (isf32) ((float*)out)[b*256 + p] = rr;
    else       ((unsigned short*)out)[b*256 + p] = f2b(rr);
  }
}

// ---------- fallback if ws too small ----------
__global__ void zero_kernel(unsigned* __restrict__ p, int n){
  const int i = blockIdx.x * 1024 + threadIdx.x;
  if (i < n) p[i] = 0;
}

// ============================================================
extern "C" void kernel_launch(void* const* d_in, const int* in_sizes, int n_in,
                              void* d_out, int out_size, void* d_ws, size_t ws_size,
                              hipStream_t stream)
{
  (void)in_sizes; (void)n_in; (void)out_size;

  if (ws_size < ((size_t)44 << 20)){
    zero_kernel<<<8, 1024, 0, stream>>>((unsigned*)d_out, 8192);
    return;
  }

  hipFuncSetAttribute((const void*)scan_kernel,
                      hipFuncAttributeMaxDynamicSharedMemorySize, SCAN_SMEM);

  char* ws = (char*)d_ws;
  int*      flag   = (int*)ws;
  int*      aflag  = (int*)(ws + 256);
  int*      cflag  = (int*)(ws + 512);
  float*    pvec   = (float*)(ws + 4096);
  uint4*    packed = (uint4*)(ws + 65536);
  unsigned* seq    = (unsigned*)(ws + ((size_t)8 << 20));     // 32 MB
  unsigned* ring   = (unsigned*)(ws + ((size_t)40 << 20));    // 512 KB
  float*    sws    = (float*)(ws + ((size_t)41 << 20));
  float*    pws    = (float*)(ws + ((size_t)41 << 20) + 524288);
  float*    qws    = (float*)(ws + ((size_t)42 << 20));
  float*    oacc   = (float*)(ws + ((size_t)42 << 20) + 262144);

  detect_kernel<<<1, 256, 0, stream>>>((const unsigned*)d_in[0], flag);
  zflags_kernel<<<1, 128, 0, stream>>>(aflag, cflag);

  PackDesc pd;
  const void* msrc[14] = {
    d_in[1], d_in[3], d_in[4], d_in[6],
    d_in[12], d_in[14], d_in[15], d_in[17],
    d_in[23], d_in[23], d_in[23],
    d_in[25], d_in[27], d_in[29]
  };
  const long eoff[14] = {0,0,0,0, 0,0,0,0, 0, 262144, 524288, 0, 0, 0};
  const int kk8[14]  = {32,64,96,64, 64,64,128,64, 64,64,64, 64, 64, 32};
  const int ln2[14]  = {9,9,9,9, 9,9,9,9, 9,9,9, 9, 8, 8};
  const int mode[14] = {0,0,0,0, 0,0,0,0, 1,1,1, 1, 1, 1};
  const int cum[15]  = {0,16384,49152,98304,131072,163840,196608,262144,
                        294912,327680,360448,393216,425984,442368,450560};
  for (int i = 0; i < 14; ++i){
    pd.src[i]=msrc[i]; pd.eoff[i]=eoff[i]; pd.kdiv8[i]=kk8[i];
    pd.lg2n[i]=ln2[i]; pd.mode[i]=mode[i];
  }
  for (int i = 0; i < 15; ++i) pd.cum[i] = cum[i];
  pack_kernel<<<(PK_TOTAL + 255)/256, 256, 0, stream>>>(pd, flag, packed);

  VecDesc vd;
  const void* vsrc[18] = {
    d_in[2], d_in[5], d_in[7], d_in[8], d_in[9], d_in[10], d_in[11],
    d_in[13], d_in[16], d_in[18], d_in[19], d_in[20], d_in[21], d_in[22],
    d_in[24], d_in[26], d_in[28], d_in[30]
  };
  const int vn[18]  = {512,512,512,512,512,512,512, 512,512,512,512,512,512,512,
                       1536,512,256,256};
  const int vds[18] = {0,512,1024,1536,2048,2560,3072,
                       3584,4096,4608,5120,5632,6144,6656,
                       7168,8704,9216,9472};
  for (int i = 0; i < 18; ++i){ vd.src[i]=vsrc[i]; vd.n[i]=vn[i]; vd.dst[i]=vds[i]; }
  vec_kernel<<<18, 512, 0, stream>>>(vd, flag, pvec);

  scan_kernel<<<128, 1024, SCAN_SMEM, stream>>>(d_in[0], packed, pvec, flag,
                                                seq, ring, aflag, cflag);
  q_kernel<<<64, 512, 0, stream>>>(seq, packed, pvec, qws);
  score_kernel<<<64*512, 512, 0, stream>>>(seq, packed, pvec, qws, sws);
  softmax_kernel<<<256, 512, 0, stream>>>(sws, pws, oacc);
  vacc_kernel<<<512, 512, 0, stream>>>(seq, packed, pvec, pws, oacc);
  final_kernel<<<64, 512, 0, stream>>>(oacc, packed, pvec, flag, d_out);
}